// Round 7
// baseline (199.579 us; speedup 1.0000x reference)
//
#include <hip/hip_runtime.h>
#include <hip/hip_fp16.h>
#include <math.h>

__device__ __forceinline__ float lrelu02(float x) { return x > 0.f ? x : 0.2f * x; }

typedef _Float16 h2_t __attribute__((ext_vector_type(2)));
__device__ __forceinline__ float fdot2(__half2 a, __half2 b, float c) {
    h2_t ha = *reinterpret_cast<h2_t*>(&a);
    h2_t hb = *reinterpret_cast<h2_t*>(&b);
    return __builtin_amdgcn_fdot2(ha, hb, c, false);
}

#define ESHIFT 10.0f   // constant shift replacing global max (alpha is ratio-invariant)
#define NCHUNK 128     // sort chunks (blocks in P1/P3)

// ============ CSR build: tile counting sort, NO global atomics ============
// bucket = trg >> 8 (256 nodes per bucket), nbk = ceil(N/256) <= 256

// P1: per-chunk histogram
__global__ __launch_bounds__(1024) void sort_hist_kernel(
    const int* __restrict__ trg, int* __restrict__ H, int E, int nbk, int chunk)
{
    __shared__ int hist[256];
    int c = blockIdx.x, t = threadIdx.x;
    if (t < 256) hist[t] = 0;
    __syncthreads();
    int e0 = c * chunk, e1 = min(e0 + chunk, E);
    for (int i = e0 + t; i < e1; i += 1024)
        atomicAdd(&hist[trg[i] >> 8], 1);
    __syncthreads();
    if (t < nbk) H[c * nbk + t] = hist[t];
}

// P2: column-sum over chunks, scan buckets, per-(chunk,bucket) bases (+rowptr tail)
__global__ __launch_bounds__(256) void sort_scan_kernel(
    const int* __restrict__ H, int* __restrict__ base,
    int* __restrict__ bktstart, int* __restrict__ rowptr,
    int nbk, int nchunks, int E)
{
    __shared__ int sm[256];
    int t = threadIdx.x;
    int tot = 0;
    if (t < nbk)
        for (int c = 0; c < nchunks; ++c) tot += H[c * nbk + t];
    sm[t] = tot;
    __syncthreads();
    for (int off = 1; off < 256; off <<= 1) {
        int x = (t >= off) ? sm[t - off] : 0;
        __syncthreads();
        sm[t] += x;
        __syncthreads();
    }
    int excl = sm[t] - tot;
    if (t < nbk) {
        bktstart[t] = excl;
        int run = excl;
        for (int c = 0; c < nchunks; ++c) { base[c * nbk + t] = run; run += H[c * nbk + t]; }
    }
    if (t == 0) { bktstart[nbk] = E; rowptr[nbk * 256] = E; }
}

// P3: scatter (src,trg) pairs bucket-major via LDS cursors (no global atomics)
__global__ __launch_bounds__(1024) void sort_scatter_kernel(
    const int* __restrict__ src, const int* __restrict__ trg,
    const int* __restrict__ base, int2* __restrict__ stage,
    int E, int nbk, int chunk)
{
    __shared__ int cur[256];
    int c = blockIdx.x, t = threadIdx.x;
    if (t < nbk) cur[t] = base[c * nbk + t];
    __syncthreads();
    int e0 = c * chunk, e1 = min(e0 + chunk, E);
    for (int i = e0 + t; i < e1; i += 1024) {
        int tg = trg[i];
        int pos = atomicAdd(&cur[tg >> 8], 1);
        stage[pos] = make_int2(src[i], tg);
    }
}

// P4: one block per bucket: node histogram -> scan -> rowptr + colsrc
__global__ __launch_bounds__(256) void sort_finalize_kernel(
    const int2* __restrict__ stage, const int* __restrict__ bktstart,
    int* __restrict__ rowptr, int* __restrict__ colsrc, int nbk)
{
    __shared__ int hist[256];
    __shared__ int sm[256];
    __shared__ int cur[256];
    int b = blockIdx.x, t = threadIdx.x;
    int s0 = bktstart[b], cnt = bktstart[b + 1] - s0;
    hist[t] = 0;
    __syncthreads();
    for (int i = t; i < cnt; i += 256)
        atomicAdd(&hist[stage[s0 + i].y & 255], 1);
    __syncthreads();
    int h = hist[t];
    sm[t] = h;
    __syncthreads();
    for (int off = 1; off < 256; off <<= 1) {
        int x = (t >= off) ? sm[t - off] : 0;
        __syncthreads();
        sm[t] += x;
        __syncthreads();
    }
    int excl = sm[t] - h;
    cur[t] = s0 + excl;
    rowptr[b * 256 + t] = s0 + excl;
    __syncthreads();
    for (int i = t; i < cnt; i += 256) {
        int2 p = stage[s0 + i];
        int pos = atomicAdd(&cur[p.y & 255], 1);
        colsrc[pos] = p.x;
    }
}

// ---------------- Layer-0 projection (4 nodes x 4 ch per thread, v_dot2) --------
// w2_s[f2][c] = half2(w[2*f2][c], w[2*f2+1][c]), c = h*16+o.  16KB LDS.
union F4H { float4 f; __half2 h[4]; };

__global__ __launch_bounds__(256) void gemm0_kernel(
    const float* __restrict__ stat, const float* __restrict__ dyn0,
    const float* __restrict__ dyn1, const float* __restrict__ w0,
    const float* __restrict__ asrc0, const float* __restrict__ atrg0,
    __half2* __restrict__ hp0h, float* __restrict__ s0, float* __restrict__ t0,
    int n_nodes)
{
    __shared__ __half2 w2_s[64 * 128];   // [f2][c], 16KB
    int t = threadIdx.x;
    for (int i = t; i < 8192; i += 256) {
        int f2 = i >> 7, c = i & 127;
        int h = c >> 4, o = c & 15;
        float a = w0[h * 2048 + (2 * f2) * 16 + o];
        float b = w0[h * 2048 + (2 * f2 + 1) * 16 + o];
        w2_s[i] = __floats2half2_rn(a, b);
    }
    __syncthreads();

    int cg = t & 31, ns = t >> 5;
    int c0 = cg * 4;
    int h = c0 >> 4, o0 = c0 & 15;
    float4 asv = *reinterpret_cast<const float4*>(&asrc0[h * 16 + o0]);
    float4 atv = *reinterpret_cast<const float4*>(&atrg0[h * 16 + o0]);

    int ntiles = (n_nodes + 31) >> 5;
    for (int tile = blockIdx.x; tile < ntiles; tile += gridDim.x) {
        int nb = tile * 32 + ns * 4;
        int nn[4] = { nb, nb + 1, nb + 2, nb + 3 };
        int nc[4];
#pragma unroll
        for (int i = 0; i < 4; ++i) nc[i] = min(nn[i], n_nodes - 1);

        float acc[4][4];
#pragma unroll
        for (int i = 0; i < 4; ++i)
#pragma unroll
            for (int j = 0; j < 4; ++j) acc[i][j] = 0.f;

        // ---- dyn0: f2 in [0,16) ----
#pragma unroll 2
        for (int fq = 0; fq < 8; ++fq) {
            __half2 eh[4][2];
#pragma unroll
            for (int i = 0; i < 4; ++i) {
                float4 v = *reinterpret_cast<const float4*>(&dyn0[(size_t)nc[i] * 32 + fq * 4]);
                eh[i][0] = __floats2half2_rn(v.x, v.y);
                eh[i][1] = __floats2half2_rn(v.z, v.w);
            }
#pragma unroll
            for (int p = 0; p < 2; ++p) {
                F4H wu; wu.f = *reinterpret_cast<const float4*>(&w2_s[(fq * 2 + p) * 128 + c0]);
#pragma unroll
                for (int i = 0; i < 4; ++i) {
                    acc[i][0] = fdot2(eh[i][p], wu.h[0], acc[i][0]);
                    acc[i][1] = fdot2(eh[i][p], wu.h[1], acc[i][1]);
                    acc[i][2] = fdot2(eh[i][p], wu.h[2], acc[i][2]);
                    acc[i][3] = fdot2(eh[i][p], wu.h[3], acc[i][3]);
                }
            }
        }
        // ---- dyn1: f2 in [16,32) ----
#pragma unroll 2
        for (int fq = 0; fq < 8; ++fq) {
            __half2 eh[4][2];
#pragma unroll
            for (int i = 0; i < 4; ++i) {
                float4 v = *reinterpret_cast<const float4*>(&dyn1[(size_t)nc[i] * 32 + fq * 4]);
                eh[i][0] = __floats2half2_rn(v.x, v.y);
                eh[i][1] = __floats2half2_rn(v.z, v.w);
            }
#pragma unroll
            for (int p = 0; p < 2; ++p) {
                F4H wu; wu.f = *reinterpret_cast<const float4*>(&w2_s[(16 + fq * 2 + p) * 128 + c0]);
#pragma unroll
                for (int i = 0; i < 4; ++i) {
                    acc[i][0] = fdot2(eh[i][p], wu.h[0], acc[i][0]);
                    acc[i][1] = fdot2(eh[i][p], wu.h[1], acc[i][1]);
                    acc[i][2] = fdot2(eh[i][p], wu.h[2], acc[i][2]);
                    acc[i][3] = fdot2(eh[i][p], wu.h[3], acc[i][3]);
                }
            }
        }
        // ---- stat: f2 in [32,64) ----
#pragma unroll 2
        for (int fq = 0; fq < 16; ++fq) {
            __half2 eh[4][2];
#pragma unroll
            for (int i = 0; i < 4; ++i) {
                float4 v = *reinterpret_cast<const float4*>(&stat[(size_t)nc[i] * 64 + fq * 4]);
                eh[i][0] = __floats2half2_rn(v.x, v.y);
                eh[i][1] = __floats2half2_rn(v.z, v.w);
            }
#pragma unroll
            for (int p = 0; p < 2; ++p) {
                F4H wu; wu.f = *reinterpret_cast<const float4*>(&w2_s[(32 + fq * 2 + p) * 128 + c0]);
#pragma unroll
                for (int i = 0; i < 4; ++i) {
                    acc[i][0] = fdot2(eh[i][p], wu.h[0], acc[i][0]);
                    acc[i][1] = fdot2(eh[i][p], wu.h[1], acc[i][1]);
                    acc[i][2] = fdot2(eh[i][p], wu.h[2], acc[i][2]);
                    acc[i][3] = fdot2(eh[i][p], wu.h[3], acc[i][3]);
                }
            }
        }

#pragma unroll
        for (int i = 0; i < 4; ++i) {
            bool valid = nn[i] < n_nodes;
            if (valid) {
                hp0h[(size_t)nn[i] * 64 + (c0 >> 1)]     = __floats2half2_rn(acc[i][0], acc[i][1]);
                hp0h[(size_t)nn[i] * 64 + (c0 >> 1) + 1] = __floats2half2_rn(acc[i][2], acc[i][3]);
            }
            float ps = acc[i][0] * asv.x + acc[i][1] * asv.y + acc[i][2] * asv.z + acc[i][3] * asv.w;
            float pt = acc[i][0] * atv.x + acc[i][1] * atv.y + acc[i][2] * atv.z + acc[i][3] * atv.w;
            ps += __shfl_xor(ps, 1); ps += __shfl_xor(ps, 2);
            pt += __shfl_xor(pt, 1); pt += __shfl_xor(pt, 2);
            if ((cg & 3) == 0 && valid) {
                s0[nn[i] * 8 + h] = ps;
                t0[nn[i] * 8 + h] = pt;
            }
        }
    }
}

// ---------------- Layer-0 aggregate: one WAVE per target node ----------------
#define CH 64
__global__ __launch_bounds__(256) void node_accum0_kernel(
    const int* __restrict__ rowptr, const int* __restrict__ colsrc,
    const float* __restrict__ s0, const float* __restrict__ t0,
    const __half2* __restrict__ hp0h, const float* __restrict__ w1,
    const float* __restrict__ asrc1, const float* __restrict__ atrg1,
    float4* __restrict__ pk1, float* __restrict__ t1, int n_nodes)
{
    __shared__ int   se_s[4][CH];
    __shared__ float p_s[4][CH * 8];

    int w = threadIdx.x >> 6;
    int l = threadIdx.x & 63;
    int n = blockIdx.x * 4 + w;
    if (n >= n_nodes) return;

    int start = rowptr[n];
    int deg = rowptr[n + 1] - start;
    int hl = l & 7;          // head for p-compute
    int hc = l >> 3;         // head of my channels
    float tval = t0[n * 8 + hl];
    const float* pw = p_s[w];

    float acc0 = 0.f, acc1 = 0.f, dsum = 0.f;
    for (int chunk = 0; chunk < deg; chunk += CH) {
        int m = min(CH, deg - chunk);
        if (l < m) se_s[w][l] = colsrc[start + chunk + l];
        __builtin_amdgcn_wave_barrier();
        int iters = (m + 7) >> 3;
        for (int r = 0; r < iters; ++r) {
            int e = r * 8 + (l >> 3);
            float p = 0.f;
            if (e < m) {
                int se = se_s[w][e];
                float x = s0[se * 8 + hl] + tval;
                p = __expf(lrelu02(x) - ESHIFT);
            }
            p_s[w][r * 64 + l] = p;   // == p_s[e*8 + hl]
            dsum += p;
        }
        __builtin_amdgcn_wave_barrier();
        int e = 0;
        for (; e + 4 <= m; e += 4) {
            int sa = se_s[w][e + 0], sb = se_s[w][e + 1];
            int sc = se_s[w][e + 2], sd = se_s[w][e + 3];
            float2 fa = __half22float2(hp0h[(size_t)sa * 64 + l]);
            float2 fb = __half22float2(hp0h[(size_t)sb * 64 + l]);
            float2 fc = __half22float2(hp0h[(size_t)sc * 64 + l]);
            float2 fd = __half22float2(hp0h[(size_t)sd * 64 + l]);
            float pa = pw[(e + 0) * 8 + hc], pb = pw[(e + 1) * 8 + hc];
            float pc2 = pw[(e + 2) * 8 + hc], pd = pw[(e + 3) * 8 + hc];
            acc0 += fa.x * pa; acc1 += fa.y * pa;
            acc0 += fb.x * pb; acc1 += fb.y * pb;
            acc0 += fc.x * pc2; acc1 += fc.y * pc2;
            acc0 += fd.x * pd; acc1 += fd.y * pd;
        }
        for (; e < m; ++e) {
            int sa = se_s[w][e];
            float2 fa = __half22float2(hp0h[(size_t)sa * 64 + l]);
            float pa = pw[e * 8 + hc];
            acc0 += fa.x * pa; acc1 += fa.y * pa;
        }
        __builtin_amdgcn_wave_barrier();
    }

    dsum += __shfl_xor(dsum, 8);
    dsum += __shfl_xor(dsum, 16);
    dsum += __shfl_xor(dsum, 32);
    float denom = __shfl(dsum, hc);
    float inv = 1.f / (denom + 1e-16f);
    float v0 = acc0 * inv; v0 = v0 > 0.f ? v0 : expm1f(v0);
    float v1 = acc1 * inv; v1 = v1 > 0.f ? v1 : expm1f(v1);

    float4 wv = *reinterpret_cast<const float4*>(&w1[l * 4]);
    float r0 = v0 * wv.x + v1 * wv.z;
    float r1 = v0 * wv.y + v1 * wv.w;
#pragma unroll
    for (int off = 32; off > 0; off >>= 1) {
        r0 += __shfl_down(r0, off);
        r1 += __shfl_down(r1, off);
    }
    if (l == 0) {
        float s1v = r0 * asrc1[0] + r1 * asrc1[1];
        float t1v = r0 * atrg1[0] + r1 * atrg1[1];
        float4 pk; pk.x = r0; pk.y = r1; pk.z = s1v; pk.w = 0.f;
        pk1[n] = pk;
        t1[n] = t1v;
    }
}

// ---------------- Layer-1 aggregate + mean + log_softmax -> out ----------------
__global__ __launch_bounds__(256) void node_accum1_kernel(
    const int* __restrict__ rowptr, const int* __restrict__ colsrc,
    const float4* __restrict__ pk1, const float* __restrict__ t1,
    float* __restrict__ out, int n_nodes)
{
    int lane = threadIdx.x & 63;
    int n = blockIdx.x * 4 + (threadIdx.x >> 6);
    if (n >= n_nodes) return;
    int start = rowptr[n], deg = rowptr[n + 1] - start;
    float tn = t1[n];
    float d = 0.f, a0 = 0.f, a1 = 0.f;
    for (int i = lane; i < deg; i += 64) {
        int se = colsrc[start + i];
        float4 q = pk1[se];
        float p = __expf(lrelu02(q.z + tn) - ESHIFT);
        d += p;
        a0 += p * q.x;
        a1 += p * q.y;
    }
#pragma unroll
    for (int off = 32; off > 0; off >>= 1) {
        d  += __shfl_down(d, off);
        a0 += __shfl_down(a0, off);
        a1 += __shfl_down(a1, off);
    }
    if (lane == 0) {
        float inv = 1.f / (d + 1e-16f);
        float x0 = a0 * inv, x1 = a1 * inv;
        float m = fmaxf(x0, x1);
        float lse = m + logf(__expf(x0 - m) + __expf(x1 - m));
        out[n * 2 + 0] = x0 - lse;
        out[n * 2 + 1] = x1 - lse;
    }
}

extern "C" void kernel_launch(void* const* d_in, const int* in_sizes, int n_in,
                              void* d_out, int out_size, void* d_ws, size_t ws_size,
                              hipStream_t stream) {
    const float* stat  = (const float*)d_in[0];
    const float* dyn0  = (const float*)d_in[1];
    const float* dyn1  = (const float*)d_in[2];
    const int*   src   = (const int*)d_in[3];
    const int*   trg   = (const int*)d_in[4];
    const float* w0    = (const float*)d_in[5];
    const float* asrc0 = (const float*)d_in[6];
    const float* atrg0 = (const float*)d_in[7];
    const float* w1    = (const float*)d_in[8];
    const float* asrc1 = (const float*)d_in[9];
    const float* atrg1 = (const float*)d_in[10];
    float* out = (float*)d_out;

    const int N = in_sizes[0] / 64;   // 50000
    const int E = in_sizes[3];        // 800000
    const int NBK = (N + 255) >> 8;   // 196 buckets of 256 nodes
    const int CHUNK = (E + NCHUNK - 1) / NCHUNK;

    // ---- workspace layout ----
    float* ws = (float*)d_ws;
    size_t off = 0;
    // hp0h region (N*64 floats = 12.8MB); staging pairs (E int2 = 6.4MB) alias it
    __half2* hp0h = (__half2*)(ws + off);
    int2*    stage = (int2*)(ws + off);
    off += (size_t)N * 64;
    float* s0  = ws + off; off += (size_t)N * 8;
    float* t0  = ws + off; off += (size_t)N * 8;
    float4* pk1 = (float4*)(ws + off); off += (size_t)N * 4;
    float* t1  = ws + off; off += (size_t)N;
    off = (off + 3) & ~(size_t)3;
    int* iws      = (int*)(ws + off);
    int* rowptr   = iws;                        // NBK*256 + 1
    int* colsrc   = rowptr + NBK * 256 + 1;     // E
    int* H        = colsrc + E;                 // NCHUNK*NBK
    int* basearr  = H + NCHUNK * NBK;           // NCHUNK*NBK
    int* bktstart = basearr + NCHUNK * NBK;     // NBK+1

    // ---- CSR build (tile counting sort, no global atomics) ----
    sort_hist_kernel<<<NCHUNK, 1024, 0, stream>>>(trg, H, E, NBK, CHUNK);
    sort_scan_kernel<<<1, 256, 0, stream>>>(H, basearr, bktstart, rowptr, NBK, NCHUNK, E);
    sort_scatter_kernel<<<NCHUNK, 1024, 0, stream>>>(src, trg, basearr, stage, E, NBK, CHUNK);
    sort_finalize_kernel<<<NBK, 256, 0, stream>>>(stage, bktstart, rowptr, colsrc, NBK);

    // ---- layer 0 projection + scores (writes hp0h over the staging region) ----
    gemm0_kernel<<<640, 256, 0, stream>>>(
        stat, dyn0, dyn1, w0, asrc0, atrg0, hp0h, s0, t0, N);

    // ---- layer 0 aggregate + ELU + W1 + layer-1 scores (wave per node) ----
    node_accum0_kernel<<<(N + 3) / 4, 256, 0, stream>>>(
        rowptr, colsrc, s0, t0, hp0h, w1, asrc1, atrg1, pk1, t1, N);

    // ---- layer 1 aggregate + mean + log_softmax ----
    node_accum1_kernel<<<(N + 3) / 4, 256, 0, stream>>>(
        rowptr, colsrc, pk1, t1, out, N);
}

// Round 8
// 192.037 us; speedup vs baseline: 1.0393x; 1.0393x over previous
//
#include <hip/hip_runtime.h>
#include <hip/hip_fp16.h>
#include <math.h>

__device__ __forceinline__ float lrelu02(float x) { return x > 0.f ? x : 0.2f * x; }

typedef _Float16 h2_t __attribute__((ext_vector_type(2)));
__device__ __forceinline__ float fdot2(__half2 a, __half2 b, float c) {
    h2_t ha = *reinterpret_cast<h2_t*>(&a);
    h2_t hb = *reinterpret_cast<h2_t*>(&b);
    return __builtin_amdgcn_fdot2(ha, hb, c, false);
}

#define ESHIFT 10.0f   // constant shift replacing global max (alpha is ratio-invariant)
#define NCHUNK 128     // sort chunks (blocks in P1/P3)

// ============ CSR build: tile counting sort, NO global atomics ============
// bucket = trg >> 8 (256 nodes per bucket), nbk = ceil(N/256) <= 256

// P1: per-chunk histogram
__global__ __launch_bounds__(1024) void sort_hist_kernel(
    const int* __restrict__ trg, int* __restrict__ H, int E, int nbk, int chunk)
{
    __shared__ int hist[256];
    int c = blockIdx.x, t = threadIdx.x;
    if (t < 256) hist[t] = 0;
    __syncthreads();
    int e0 = c * chunk, e1 = min(e0 + chunk, E);
    for (int i = e0 + t; i < e1; i += 1024)
        atomicAdd(&hist[trg[i] >> 8], 1);
    __syncthreads();
    if (t < nbk) H[c * nbk + t] = hist[t];
}

// P2: column-sum over chunks, scan buckets, per-(chunk,bucket) bases (+rowptr tail)
__global__ __launch_bounds__(256) void sort_scan_kernel(
    const int* __restrict__ H, int* __restrict__ base,
    int* __restrict__ bktstart, int* __restrict__ rowptr,
    int nbk, int nchunks, int E)
{
    __shared__ int sm[256];
    int t = threadIdx.x;
    int tot = 0;
    if (t < nbk)
        for (int c = 0; c < nchunks; ++c) tot += H[c * nbk + t];
    sm[t] = tot;
    __syncthreads();
    for (int off = 1; off < 256; off <<= 1) {
        int x = (t >= off) ? sm[t - off] : 0;
        __syncthreads();
        sm[t] += x;
        __syncthreads();
    }
    int excl = sm[t] - tot;
    if (t < nbk) {
        bktstart[t] = excl;
        int run = excl;
        for (int c = 0; c < nchunks; ++c) { base[c * nbk + t] = run; run += H[c * nbk + t]; }
    }
    if (t == 0) { bktstart[nbk] = E; rowptr[nbk * 256] = E; }
}

// P3: scatter (src,trg) pairs bucket-major via LDS cursors (no global atomics)
__global__ __launch_bounds__(1024) void sort_scatter_kernel(
    const int* __restrict__ src, const int* __restrict__ trg,
    const int* __restrict__ base, int2* __restrict__ stage,
    int E, int nbk, int chunk)
{
    __shared__ int cur[256];
    int c = blockIdx.x, t = threadIdx.x;
    if (t < nbk) cur[t] = base[c * nbk + t];
    __syncthreads();
    int e0 = c * chunk, e1 = min(e0 + chunk, E);
    for (int i = e0 + t; i < e1; i += 1024) {
        int tg = trg[i];
        int pos = atomicAdd(&cur[tg >> 8], 1);
        stage[pos] = make_int2(src[i], tg);
    }
}

// P4: one block per bucket: node histogram -> scan -> rowptr + colsrc
__global__ __launch_bounds__(256) void sort_finalize_kernel(
    const int2* __restrict__ stage, const int* __restrict__ bktstart,
    int* __restrict__ rowptr, int* __restrict__ colsrc, int nbk)
{
    __shared__ int hist[256];
    __shared__ int sm[256];
    __shared__ int cur[256];
    int b = blockIdx.x, t = threadIdx.x;
    int s0 = bktstart[b], cnt = bktstart[b + 1] - s0;
    hist[t] = 0;
    __syncthreads();
    for (int i = t; i < cnt; i += 256)
        atomicAdd(&hist[stage[s0 + i].y & 255], 1);
    __syncthreads();
    int h = hist[t];
    sm[t] = h;
    __syncthreads();
    for (int off = 1; off < 256; off <<= 1) {
        int x = (t >= off) ? sm[t - off] : 0;
        __syncthreads();
        sm[t] += x;
        __syncthreads();
    }
    int excl = sm[t] - h;
    cur[t] = s0 + excl;
    rowptr[b * 256 + t] = s0 + excl;
    __syncthreads();
    for (int i = t; i < cnt; i += 256) {
        int2 p = stage[s0 + i];
        int pos = atomicAdd(&cur[p.y & 255], 1);
        colsrc[pos] = p.x;
    }
}

// ---------------- Layer-0 projection (4 nodes x 4 ch per thread, v_dot2) --------
// w2_s[f2][c] = half2(w[2*f2][c], w[2*f2+1][c]), c = h*16+o.  32KB LDS.
union F4H { float4 f; __half2 h[4]; };

__global__ __launch_bounds__(256) void gemm0_kernel(
    const float* __restrict__ stat, const float* __restrict__ dyn0,
    const float* __restrict__ dyn1, const float* __restrict__ w0,
    const float* __restrict__ asrc0, const float* __restrict__ atrg0,
    __half2* __restrict__ hp0h, float* __restrict__ s0, float* __restrict__ t0,
    int n_nodes)
{
    __shared__ __half2 w2_s[64 * 128];   // [f2][c], 32KB
    int t = threadIdx.x;
    for (int i = t; i < 8192; i += 256) {
        int f2 = i >> 7, c = i & 127;
        int h = c >> 4, o = c & 15;
        float a = w0[h * 2048 + (2 * f2) * 16 + o];
        float b = w0[h * 2048 + (2 * f2 + 1) * 16 + o];
        w2_s[i] = __floats2half2_rn(a, b);
    }
    __syncthreads();

    int cg = t & 31, ns = t >> 5;
    int c0 = cg * 4;
    int h = c0 >> 4, o0 = c0 & 15;
    float4 asv = *reinterpret_cast<const float4*>(&asrc0[h * 16 + o0]);
    float4 atv = *reinterpret_cast<const float4*>(&atrg0[h * 16 + o0]);

    int ntiles = (n_nodes + 31) >> 5;
    for (int tile = blockIdx.x; tile < ntiles; tile += gridDim.x) {
        int nb = tile * 32 + ns * 4;
        int nn[4] = { nb, nb + 1, nb + 2, nb + 3 };
        int nc[4];
#pragma unroll
        for (int i = 0; i < 4; ++i) nc[i] = min(nn[i], n_nodes - 1);

        float acc[4][4];
#pragma unroll
        for (int i = 0; i < 4; ++i)
#pragma unroll
            for (int j = 0; j < 4; ++j) acc[i][j] = 0.f;

        // ---- dyn0: f2 in [0,16) ----
#pragma unroll 2
        for (int fq = 0; fq < 8; ++fq) {
            __half2 eh[4][2];
#pragma unroll
            for (int i = 0; i < 4; ++i) {
                float4 v = *reinterpret_cast<const float4*>(&dyn0[(size_t)nc[i] * 32 + fq * 4]);
                eh[i][0] = __floats2half2_rn(v.x, v.y);
                eh[i][1] = __floats2half2_rn(v.z, v.w);
            }
#pragma unroll
            for (int p = 0; p < 2; ++p) {
                F4H wu; wu.f = *reinterpret_cast<const float4*>(&w2_s[(fq * 2 + p) * 128 + c0]);
#pragma unroll
                for (int i = 0; i < 4; ++i) {
                    acc[i][0] = fdot2(eh[i][p], wu.h[0], acc[i][0]);
                    acc[i][1] = fdot2(eh[i][p], wu.h[1], acc[i][1]);
                    acc[i][2] = fdot2(eh[i][p], wu.h[2], acc[i][2]);
                    acc[i][3] = fdot2(eh[i][p], wu.h[3], acc[i][3]);
                }
            }
        }
        // ---- dyn1: f2 in [16,32) ----
#pragma unroll 2
        for (int fq = 0; fq < 8; ++fq) {
            __half2 eh[4][2];
#pragma unroll
            for (int i = 0; i < 4; ++i) {
                float4 v = *reinterpret_cast<const float4*>(&dyn1[(size_t)nc[i] * 32 + fq * 4]);
                eh[i][0] = __floats2half2_rn(v.x, v.y);
                eh[i][1] = __floats2half2_rn(v.z, v.w);
            }
#pragma unroll
            for (int p = 0; p < 2; ++p) {
                F4H wu; wu.f = *reinterpret_cast<const float4*>(&w2_s[(16 + fq * 2 + p) * 128 + c0]);
#pragma unroll
                for (int i = 0; i < 4; ++i) {
                    acc[i][0] = fdot2(eh[i][p], wu.h[0], acc[i][0]);
                    acc[i][1] = fdot2(eh[i][p], wu.h[1], acc[i][1]);
                    acc[i][2] = fdot2(eh[i][p], wu.h[2], acc[i][2]);
                    acc[i][3] = fdot2(eh[i][p], wu.h[3], acc[i][3]);
                }
            }
        }
        // ---- stat: f2 in [32,64) ----
#pragma unroll 2
        for (int fq = 0; fq < 16; ++fq) {
            __half2 eh[4][2];
#pragma unroll
            for (int i = 0; i < 4; ++i) {
                float4 v = *reinterpret_cast<const float4*>(&stat[(size_t)nc[i] * 64 + fq * 4]);
                eh[i][0] = __floats2half2_rn(v.x, v.y);
                eh[i][1] = __floats2half2_rn(v.z, v.w);
            }
#pragma unroll
            for (int p = 0; p < 2; ++p) {
                F4H wu; wu.f = *reinterpret_cast<const float4*>(&w2_s[(32 + fq * 2 + p) * 128 + c0]);
#pragma unroll
                for (int i = 0; i < 4; ++i) {
                    acc[i][0] = fdot2(eh[i][p], wu.h[0], acc[i][0]);
                    acc[i][1] = fdot2(eh[i][p], wu.h[1], acc[i][1]);
                    acc[i][2] = fdot2(eh[i][p], wu.h[2], acc[i][2]);
                    acc[i][3] = fdot2(eh[i][p], wu.h[3], acc[i][3]);
                }
            }
        }

#pragma unroll
        for (int i = 0; i < 4; ++i) {
            bool valid = nn[i] < n_nodes;
            if (valid) {
                hp0h[(size_t)nn[i] * 64 + (c0 >> 1)]     = __floats2half2_rn(acc[i][0], acc[i][1]);
                hp0h[(size_t)nn[i] * 64 + (c0 >> 1) + 1] = __floats2half2_rn(acc[i][2], acc[i][3]);
            }
            float ps = acc[i][0] * asv.x + acc[i][1] * asv.y + acc[i][2] * asv.z + acc[i][3] * asv.w;
            float pt = acc[i][0] * atv.x + acc[i][1] * atv.y + acc[i][2] * atv.z + acc[i][3] * atv.w;
            ps += __shfl_xor(ps, 1); ps += __shfl_xor(ps, 2);
            pt += __shfl_xor(pt, 1); pt += __shfl_xor(pt, 2);
            if ((cg & 3) == 0 && valid) {
                s0[nn[i] * 8 + h] = ps;
                t0[nn[i] * 8 + h] = pt;
            }
        }
    }
}

// ---------------- Layer-0 aggregate: one WAVE per target node ----------------
#define CH 64
__global__ __launch_bounds__(256) void node_accum0_kernel(
    const int* __restrict__ rowptr, const int* __restrict__ colsrc,
    const float* __restrict__ s0, const float* __restrict__ t0,
    const __half2* __restrict__ hp0h, const float* __restrict__ w1,
    const float* __restrict__ asrc1, const float* __restrict__ atrg1,
    float4* __restrict__ pk1, float* __restrict__ t1, int n_nodes)
{
    __shared__ int   se_s[4][CH];
    __shared__ float p_s[4][CH * 8];

    int w = threadIdx.x >> 6;
    int l = threadIdx.x & 63;
    int n = blockIdx.x * 4 + w;
    if (n >= n_nodes) return;

    int start = rowptr[n];
    int deg = rowptr[n + 1] - start;
    int hl = l & 7;          // head for p-compute
    int hc = l >> 3;         // head of my channels
    float tval = t0[n * 8 + hl];
    const float* pw = p_s[w];

    float acc0 = 0.f, acc1 = 0.f, dsum = 0.f;
    for (int chunk = 0; chunk < deg; chunk += CH) {
        int m = min(CH, deg - chunk);
        if (l < m) se_s[w][l] = colsrc[start + chunk + l];
        __builtin_amdgcn_wave_barrier();
        int iters = (m + 7) >> 3;
        for (int r = 0; r < iters; ++r) {
            int e = r * 8 + (l >> 3);
            float p = 0.f;
            if (e < m) {
                int se = se_s[w][e];
                float x = s0[se * 8 + hl] + tval;
                p = __expf(lrelu02(x) - ESHIFT);
            }
            p_s[w][r * 64 + l] = p;   // == p_s[e*8 + hl]
            dsum += p;
        }
        __builtin_amdgcn_wave_barrier();
        int e = 0;
        for (; e + 4 <= m; e += 4) {
            int sa = se_s[w][e + 0], sb = se_s[w][e + 1];
            int sc = se_s[w][e + 2], sd = se_s[w][e + 3];
            float2 fa = __half22float2(hp0h[(size_t)sa * 64 + l]);
            float2 fb = __half22float2(hp0h[(size_t)sb * 64 + l]);
            float2 fc = __half22float2(hp0h[(size_t)sc * 64 + l]);
            float2 fd = __half22float2(hp0h[(size_t)sd * 64 + l]);
            float pa = pw[(e + 0) * 8 + hc], pb = pw[(e + 1) * 8 + hc];
            float pc2 = pw[(e + 2) * 8 + hc], pd = pw[(e + 3) * 8 + hc];
            acc0 += fa.x * pa; acc1 += fa.y * pa;
            acc0 += fb.x * pb; acc1 += fb.y * pb;
            acc0 += fc.x * pc2; acc1 += fc.y * pc2;
            acc0 += fd.x * pd; acc1 += fd.y * pd;
        }
        for (; e < m; ++e) {
            int sa = se_s[w][e];
            float2 fa = __half22float2(hp0h[(size_t)sa * 64 + l]);
            float pa = pw[e * 8 + hc];
            acc0 += fa.x * pa; acc1 += fa.y * pa;
        }
        __builtin_amdgcn_wave_barrier();
    }

    dsum += __shfl_xor(dsum, 8);
    dsum += __shfl_xor(dsum, 16);
    dsum += __shfl_xor(dsum, 32);
    float denom = __shfl(dsum, hc);
    float inv = 1.f / (denom + 1e-16f);
    float v0 = acc0 * inv; v0 = v0 > 0.f ? v0 : expm1f(v0);
    float v1 = acc1 * inv; v1 = v1 > 0.f ? v1 : expm1f(v1);

    float4 wv = *reinterpret_cast<const float4*>(&w1[l * 4]);
    float r0 = v0 * wv.x + v1 * wv.z;
    float r1 = v0 * wv.y + v1 * wv.w;
#pragma unroll
    for (int off = 32; off > 0; off >>= 1) {
        r0 += __shfl_down(r0, off);
        r1 += __shfl_down(r1, off);
    }
    if (l == 0) {
        float s1v = r0 * asrc1[0] + r1 * asrc1[1];
        float t1v = r0 * atrg1[0] + r1 * atrg1[1];
        float4 pk; pk.x = r0; pk.y = r1; pk.z = s1v; pk.w = 0.f;
        pk1[n] = pk;
        t1[n] = t1v;
    }
}

// ---------------- Layer-1 aggregate + mean + log_softmax -> out ----------------
__global__ __launch_bounds__(256) void node_accum1_kernel(
    const int* __restrict__ rowptr, const int* __restrict__ colsrc,
    const float4* __restrict__ pk1, const float* __restrict__ t1,
    float* __restrict__ out, int n_nodes)
{
    int lane = threadIdx.x & 63;
    int n = blockIdx.x * 4 + (threadIdx.x >> 6);
    if (n >= n_nodes) return;
    int start = rowptr[n], deg = rowptr[n + 1] - start;
    float tn = t1[n];
    float d = 0.f, a0 = 0.f, a1 = 0.f;
    for (int i = lane; i < deg; i += 64) {
        int se = colsrc[start + i];
        float4 q = pk1[se];
        float p = __expf(lrelu02(q.z + tn) - ESHIFT);
        d += p;
        a0 += p * q.x;
        a1 += p * q.y;
    }
#pragma unroll
    for (int off = 32; off > 0; off >>= 1) {
        d  += __shfl_down(d, off);
        a0 += __shfl_down(a0, off);
        a1 += __shfl_down(a1, off);
    }
    if (lane == 0) {
        float inv = 1.f / (d + 1e-16f);
        float x0 = a0 * inv, x1 = a1 * inv;
        float m = fmaxf(x0, x1);
        float lse = m + logf(__expf(x0 - m) + __expf(x1 - m));
        out[n * 2 + 0] = x0 - lse;
        out[n * 2 + 1] = x1 - lse;
    }
}

extern "C" void kernel_launch(void* const* d_in, const int* in_sizes, int n_in,
                              void* d_out, int out_size, void* d_ws, size_t ws_size,
                              hipStream_t stream) {
    const float* stat  = (const float*)d_in[0];
    const float* dyn0  = (const float*)d_in[1];
    const float* dyn1  = (const float*)d_in[2];
    const int*   src   = (const int*)d_in[3];
    const int*   trg   = (const int*)d_in[4];
    const float* w0    = (const float*)d_in[5];
    const float* asrc0 = (const float*)d_in[6];
    const float* atrg0 = (const float*)d_in[7];
    const float* w1    = (const float*)d_in[8];
    const float* asrc1 = (const float*)d_in[9];
    const float* atrg1 = (const float*)d_in[10];
    float* out = (float*)d_out;

    const int N = in_sizes[0] / 64;   // 50000
    const int E = in_sizes[3];        // 800000
    const int NBK = (N + 255) >> 8;   // 196 buckets of 256 nodes
    const int CHUNK = (E + NCHUNK - 1) / NCHUNK;

    // ---- workspace layout ----
    float* ws = (float*)d_ws;
    size_t off = 0;
    // hp0h region (N*64 floats = 12.8MB); staging pairs (E int2 = 6.4MB) alias it
    __half2* hp0h = (__half2*)(ws + off);
    int2*    stage = (int2*)(ws + off);
    off += (size_t)N * 64;
    float* s0  = ws + off; off += (size_t)N * 8;
    float* t0  = ws + off; off += (size_t)N * 8;
    float4* pk1 = (float4*)(ws + off); off += (size_t)N * 4;
    float* t1  = ws + off; off += (size_t)N;
    off = (off + 3) & ~(size_t)3;
    int* iws      = (int*)(ws + off);
    int* rowptr   = iws;                        // NBK*256 + 1
    int* colsrc   = rowptr + NBK * 256 + 1;     // E
    int* H        = colsrc + E;                 // NCHUNK*NBK
    int* basearr  = H + NCHUNK * NBK;           // NCHUNK*NBK
    int* bktstart = basearr + NCHUNK * NBK;     // NBK+1

    // ---- CSR build (tile counting sort, no global atomics) ----
    sort_hist_kernel<<<NCHUNK, 1024, 0, stream>>>(trg, H, E, NBK, CHUNK);
    sort_scan_kernel<<<1, 256, 0, stream>>>(H, basearr, bktstart, rowptr, NBK, NCHUNK, E);
    sort_scatter_kernel<<<NCHUNK, 1024, 0, stream>>>(src, trg, basearr, stage, E, NBK, CHUNK);
    sort_finalize_kernel<<<NBK, 256, 0, stream>>>(stage, bktstart, rowptr, colsrc, NBK);

    // ---- layer 0 projection + scores: 1280 blocks = 5 blocks/CU (32KB LDS limit) ----
    gemm0_kernel<<<1280, 256, 0, stream>>>(
        stat, dyn0, dyn1, w0, asrc0, atrg0, hp0h, s0, t0, N);

    // ---- layer 0 aggregate + ELU + W1 + layer-1 scores (wave per node) ----
    node_accum0_kernel<<<(N + 3) / 4, 256, 0, stream>>>(
        rowptr, colsrc, s0, t0, hp0h, w1, asrc1, atrg1, pk1, t1, N);

    // ---- layer 1 aggregate + mean + log_softmax ----
    node_accum1_kernel<<<(N + 3) / 4, 256, 0, stream>>>(
        rowptr, colsrc, pk1, t1, out, N);
}

// Round 11
// 178.778 us; speedup vs baseline: 1.1163x; 1.0742x over previous
//
#include <hip/hip_runtime.h>
#include <hip/hip_fp16.h>
#include <math.h>

__device__ __forceinline__ float lrelu02(float x) { return x > 0.f ? x : 0.2f * x; }

typedef _Float16 h2_t __attribute__((ext_vector_type(2)));
__device__ __forceinline__ float fdot2(__half2 a, __half2 b, float c) {
    h2_t ha = *reinterpret_cast<h2_t*>(&a);
    h2_t hb = *reinterpret_cast<h2_t*>(&b);
    return __builtin_amdgcn_fdot2(ha, hb, c, false);
}

#define ESHIFT 10.0f   // constant shift replacing global max (alpha is ratio-invariant)
#define NCHUNK 128     // sort chunks (blocks in P1/P3)

// ============ CSR build: tile counting sort, NO global atomics ============
// bucket = trg >> 8 (256 nodes per bucket), nbk = ceil(N/256) <= 256

// P1: per-chunk histogram
__global__ __launch_bounds__(1024) void sort_hist_kernel(
    const int* __restrict__ trg, int* __restrict__ H, int E, int nbk, int chunk)
{
    __shared__ int hist[256];
    int c = blockIdx.x, t = threadIdx.x;
    if (t < 256) hist[t] = 0;
    __syncthreads();
    int e0 = c * chunk, e1 = min(e0 + chunk, E);
    for (int i = e0 + t; i < e1; i += 1024)
        atomicAdd(&hist[trg[i] >> 8], 1);
    __syncthreads();
    if (t < nbk) H[c * nbk + t] = hist[t];
}

// P2: column-sum over chunks, scan buckets, per-(chunk,bucket) bases (+rowptr tail)
__global__ __launch_bounds__(256) void sort_scan_kernel(
    const int* __restrict__ H, int* __restrict__ base,
    int* __restrict__ bktstart, int* __restrict__ rowptr,
    int nbk, int nchunks, int E)
{
    __shared__ int sm[256];
    int t = threadIdx.x;
    int tot = 0;
    if (t < nbk)
        for (int c = 0; c < nchunks; ++c) tot += H[c * nbk + t];
    sm[t] = tot;
    __syncthreads();
    for (int off = 1; off < 256; off <<= 1) {
        int x = (t >= off) ? sm[t - off] : 0;
        __syncthreads();
        sm[t] += x;
        __syncthreads();
    }
    int excl = sm[t] - tot;
    if (t < nbk) {
        bktstart[t] = excl;
        int run = excl;
        for (int c = 0; c < nchunks; ++c) { base[c * nbk + t] = run; run += H[c * nbk + t]; }
    }
    if (t == 0) { bktstart[nbk] = E; rowptr[nbk * 256] = E; }
}

// P3: scatter (src,trg) pairs bucket-major via LDS cursors (no global atomics)
__global__ __launch_bounds__(1024) void sort_scatter_kernel(
    const int* __restrict__ src, const int* __restrict__ trg,
    const int* __restrict__ base, int2* __restrict__ stage,
    int E, int nbk, int chunk)
{
    __shared__ int cur[256];
    int c = blockIdx.x, t = threadIdx.x;
    if (t < nbk) cur[t] = base[c * nbk + t];
    __syncthreads();
    int e0 = c * chunk, e1 = min(e0 + chunk, E);
    for (int i = e0 + t; i < e1; i += 1024) {
        int tg = trg[i];
        int pos = atomicAdd(&cur[tg >> 8], 1);
        stage[pos] = make_int2(src[i], tg);
    }
}

// P4: one block per bucket: node histogram -> scan -> rowptr + colsrc
__global__ __launch_bounds__(256) void sort_finalize_kernel(
    const int2* __restrict__ stage, const int* __restrict__ bktstart,
    int* __restrict__ rowptr, int* __restrict__ colsrc, int nbk)
{
    __shared__ int hist[256];
    __shared__ int sm[256];
    __shared__ int cur[256];
    int b = blockIdx.x, t = threadIdx.x;
    int s0 = bktstart[b], cnt = bktstart[b + 1] - s0;
    hist[t] = 0;
    __syncthreads();
    for (int i = t; i < cnt; i += 256)
        atomicAdd(&hist[stage[s0 + i].y & 255], 1);
    __syncthreads();
    int h = hist[t];
    sm[t] = h;
    __syncthreads();
    for (int off = 1; off < 256; off <<= 1) {
        int x = (t >= off) ? sm[t - off] : 0;
        __syncthreads();
        sm[t] += x;
        __syncthreads();
    }
    int excl = sm[t] - h;
    cur[t] = s0 + excl;
    rowptr[b * 256 + t] = s0 + excl;
    __syncthreads();
    for (int i = t; i < cnt; i += 256) {
        int2 p = stage[s0 + i];
        int pos = atomicAdd(&cur[p.y & 255], 1);
        colsrc[pos] = p.x;
    }
}

// ---------------- W pre-pack: w2g[f2*128 + c] = half2(w[2f2][c], w[2f2+1][c]) ----
__global__ __launch_bounds__(256) void wconv_kernel(
    const float* __restrict__ w0, __half2* __restrict__ w2g)
{
    int i = blockIdx.x * 256 + threadIdx.x;   // 8192 entries
    if (i >= 8192) return;
    int f2 = i >> 7, c = i & 127;
    int h = c >> 4, o = c & 15;
    float a = w0[h * 2048 + (2 * f2) * 16 + o];
    float b = w0[h * 2048 + (2 * f2 + 1) * 16 + o];
    w2g[i] = __floats2half2_rn(a, b);
}

// ---------------- Layer-0 projection (4 nodes x 4 ch per thread, v_dot2) --------
// No LDS: W read as coalesced float4 from 32KB L1/L2-resident w2g.
union F4H { float4 f; __half2 h[4]; };

__global__ __launch_bounds__(256) void gemm0_kernel(
    const float* __restrict__ stat, const float* __restrict__ dyn0,
    const float* __restrict__ dyn1, const float4* __restrict__ w2g4,
    const float* __restrict__ asrc0, const float* __restrict__ atrg0,
    __half2* __restrict__ hp0h, float* __restrict__ s0, float* __restrict__ t0,
    int n_nodes)
{
    int t = threadIdx.x;
    int cg = t & 31, ns = t >> 5;
    int c0 = cg * 4;
    int h = c0 >> 4, o0 = c0 & 15;
    float4 asv = *reinterpret_cast<const float4*>(&asrc0[h * 16 + o0]);
    float4 atv = *reinterpret_cast<const float4*>(&atrg0[h * 16 + o0]);

    int nb = blockIdx.x * 32 + ns * 4;
    int nn[4] = { nb, nb + 1, nb + 2, nb + 3 };
    int nc[4];
#pragma unroll
    for (int i = 0; i < 4; ++i) nc[i] = min(nn[i], n_nodes - 1);

    float acc[4][4];
#pragma unroll
    for (int i = 0; i < 4; ++i)
#pragma unroll
        for (int j = 0; j < 4; ++j) acc[i][j] = 0.f;

    // ---- dyn0: f2 in [0,16) ----
#pragma unroll 2
    for (int fq = 0; fq < 8; ++fq) {
        __half2 eh[4][2];
#pragma unroll
        for (int i = 0; i < 4; ++i) {
            float4 v = *reinterpret_cast<const float4*>(&dyn0[(size_t)nc[i] * 32 + fq * 4]);
            eh[i][0] = __floats2half2_rn(v.x, v.y);
            eh[i][1] = __floats2half2_rn(v.z, v.w);
        }
#pragma unroll
        for (int p = 0; p < 2; ++p) {
            F4H wu; wu.f = w2g4[(fq * 2 + p) * 32 + cg];
#pragma unroll
            for (int i = 0; i < 4; ++i) {
                acc[i][0] = fdot2(eh[i][p], wu.h[0], acc[i][0]);
                acc[i][1] = fdot2(eh[i][p], wu.h[1], acc[i][1]);
                acc[i][2] = fdot2(eh[i][p], wu.h[2], acc[i][2]);
                acc[i][3] = fdot2(eh[i][p], wu.h[3], acc[i][3]);
            }
        }
    }
    // ---- dyn1: f2 in [16,32) ----
#pragma unroll 2
    for (int fq = 0; fq < 8; ++fq) {
        __half2 eh[4][2];
#pragma unroll
        for (int i = 0; i < 4; ++i) {
            float4 v = *reinterpret_cast<const float4*>(&dyn1[(size_t)nc[i] * 32 + fq * 4]);
            eh[i][0] = __floats2half2_rn(v.x, v.y);
            eh[i][1] = __floats2half2_rn(v.z, v.w);
        }
#pragma unroll
        for (int p = 0; p < 2; ++p) {
            F4H wu; wu.f = w2g4[(16 + fq * 2 + p) * 32 + cg];
#pragma unroll
            for (int i = 0; i < 4; ++i) {
                acc[i][0] = fdot2(eh[i][p], wu.h[0], acc[i][0]);
                acc[i][1] = fdot2(eh[i][p], wu.h[1], acc[i][1]);
                acc[i][2] = fdot2(eh[i][p], wu.h[2], acc[i][2]);
                acc[i][3] = fdot2(eh[i][p], wu.h[3], acc[i][3]);
            }
        }
    }
    // ---- stat: f2 in [32,64) ----
#pragma unroll 2
    for (int fq = 0; fq < 16; ++fq) {
        __half2 eh[4][2];
#pragma unroll
        for (int i = 0; i < 4; ++i) {
            float4 v = *reinterpret_cast<const float4*>(&stat[(size_t)nc[i] * 64 + fq * 4]);
            eh[i][0] = __floats2half2_rn(v.x, v.y);
            eh[i][1] = __floats2half2_rn(v.z, v.w);
        }
#pragma unroll
        for (int p = 0; p < 2; ++p) {
            F4H wu; wu.f = w2g4[(32 + fq * 2 + p) * 32 + cg];
#pragma unroll
            for (int i = 0; i < 4; ++i) {
                acc[i][0] = fdot2(eh[i][p], wu.h[0], acc[i][0]);
                acc[i][1] = fdot2(eh[i][p], wu.h[1], acc[i][1]);
                acc[i][2] = fdot2(eh[i][p], wu.h[2], acc[i][2]);
                acc[i][3] = fdot2(eh[i][p], wu.h[3], acc[i][3]);
            }
        }
    }

#pragma unroll
    for (int i = 0; i < 4; ++i) {
        bool valid = nn[i] < n_nodes;
        if (valid) {
            hp0h[(size_t)nn[i] * 64 + (c0 >> 1)]     = __floats2half2_rn(acc[i][0], acc[i][1]);
            hp0h[(size_t)nn[i] * 64 + (c0 >> 1) + 1] = __floats2half2_rn(acc[i][2], acc[i][3]);
        }
        float ps = acc[i][0] * asv.x + acc[i][1] * asv.y + acc[i][2] * asv.z + acc[i][3] * asv.w;
        float pt = acc[i][0] * atv.x + acc[i][1] * atv.y + acc[i][2] * atv.z + acc[i][3] * atv.w;
        ps += __shfl_xor(ps, 1); ps += __shfl_xor(ps, 2);
        pt += __shfl_xor(pt, 1); pt += __shfl_xor(pt, 2);
        if ((cg & 3) == 0 && valid) {
            s0[nn[i] * 8 + h] = ps;
            t0[nn[i] * 8 + h] = pt;
        }
    }
}

// ---------------- Layer-0 aggregate: one WAVE per target node ----------------
#define CH 64
__global__ __launch_bounds__(256) void node_accum0_kernel(
    const int* __restrict__ rowptr, const int* __restrict__ colsrc,
    const float* __restrict__ s0, const float* __restrict__ t0,
    const __half2* __restrict__ hp0h, const float* __restrict__ w1,
    const float* __restrict__ asrc1, const float* __restrict__ atrg1,
    float4* __restrict__ pk1, float* __restrict__ t1, int n_nodes)
{
    __shared__ int   se_s[4][CH];
    __shared__ float p_s[4][CH * 8];

    int w = threadIdx.x >> 6;
    int l = threadIdx.x & 63;
    int n = blockIdx.x * 4 + w;
    if (n >= n_nodes) return;

    int start = rowptr[n];
    int deg = rowptr[n + 1] - start;
    int hl = l & 7;          // head for p-compute
    int hc = l >> 3;         // head of my channels
    float tval = t0[n * 8 + hl];
    const float* pw = p_s[w];

    float acc0 = 0.f, acc1 = 0.f, dsum = 0.f;
    for (int chunk = 0; chunk < deg; chunk += CH) {
        int m = min(CH, deg - chunk);
        if (l < m) se_s[w][l] = colsrc[start + chunk + l];
        __builtin_amdgcn_wave_barrier();
        int iters = (m + 7) >> 3;
        for (int r = 0; r < iters; ++r) {
            int e = r * 8 + (l >> 3);
            float p = 0.f;
            if (e < m) {
                int se = se_s[w][e];
                float x = s0[se * 8 + hl] + tval;
                p = __expf(lrelu02(x) - ESHIFT);
            }
            p_s[w][r * 64 + l] = p;   // == p_s[e*8 + hl]
            dsum += p;
        }
        __builtin_amdgcn_wave_barrier();
        int e = 0;
        for (; e + 4 <= m; e += 4) {
            int sa = se_s[w][e + 0], sb = se_s[w][e + 1];
            int sc = se_s[w][e + 2], sd = se_s[w][e + 3];
            float2 fa = __half22float2(hp0h[(size_t)sa * 64 + l]);
            float2 fb = __half22float2(hp0h[(size_t)sb * 64 + l]);
            float2 fc = __half22float2(hp0h[(size_t)sc * 64 + l]);
            float2 fd = __half22float2(hp0h[(size_t)sd * 64 + l]);
            float pa = pw[(e + 0) * 8 + hc], pb = pw[(e + 1) * 8 + hc];
            float pc2 = pw[(e + 2) * 8 + hc], pd = pw[(e + 3) * 8 + hc];
            acc0 += fa.x * pa; acc1 += fa.y * pa;
            acc0 += fb.x * pb; acc1 += fb.y * pb;
            acc0 += fc.x * pc2; acc1 += fc.y * pc2;
            acc0 += fd.x * pd; acc1 += fd.y * pd;
        }
        for (; e < m; ++e) {
            int sa = se_s[w][e];
            float2 fa = __half22float2(hp0h[(size_t)sa * 64 + l]);
            float pa = pw[e * 8 + hc];
            acc0 += fa.x * pa; acc1 += fa.y * pa;
        }
        __builtin_amdgcn_wave_barrier();
    }

    dsum += __shfl_xor(dsum, 8);
    dsum += __shfl_xor(dsum, 16);
    dsum += __shfl_xor(dsum, 32);
    float denom = __shfl(dsum, hc);
    float inv = 1.f / (denom + 1e-16f);
    float v0 = acc0 * inv; v0 = v0 > 0.f ? v0 : expm1f(v0);
    float v1 = acc1 * inv; v1 = v1 > 0.f ? v1 : expm1f(v1);

    float4 wv = *reinterpret_cast<const float4*>(&w1[l * 4]);
    float r0 = v0 * wv.x + v1 * wv.z;
    float r1 = v0 * wv.y + v1 * wv.w;
#pragma unroll
    for (int off = 32; off > 0; off >>= 1) {
        r0 += __shfl_down(r0, off);
        r1 += __shfl_down(r1, off);
    }
    if (l == 0) {
        float s1v = r0 * asrc1[0] + r1 * asrc1[1];
        float t1v = r0 * atrg1[0] + r1 * atrg1[1];
        float4 pk; pk.x = r0; pk.y = r1; pk.z = s1v; pk.w = 0.f;
        pk1[n] = pk;
        t1[n] = t1v;
    }
}

// ---------------- Layer-1 aggregate + mean + log_softmax -> out ----------------
__global__ __launch_bounds__(256) void node_accum1_kernel(
    const int* __restrict__ rowptr, const int* __restrict__ colsrc,
    const float4* __restrict__ pk1, const float* __restrict__ t1,
    float* __restrict__ out, int n_nodes)
{
    int lane = threadIdx.x & 63;
    int n = blockIdx.x * 4 + (threadIdx.x >> 6);
    if (n >= n_nodes) return;
    int start = rowptr[n], deg = rowptr[n + 1] - start;
    float tn = t1[n];
    float d = 0.f, a0 = 0.f, a1 = 0.f;
    for (int i = lane; i < deg; i += 64) {
        int se = colsrc[start + i];
        float4 q = pk1[se];
        float p = __expf(lrelu02(q.z + tn) - ESHIFT);
        d += p;
        a0 += p * q.x;
        a1 += p * q.y;
    }
#pragma unroll
    for (int off = 32; off > 0; off >>= 1) {
        d  += __shfl_down(d, off);
        a0 += __shfl_down(a0, off);
        a1 += __shfl_down(a1, off);
    }
    if (lane == 0) {
        float inv = 1.f / (d + 1e-16f);
        float x0 = a0 * inv, x1 = a1 * inv;
        float m = fmaxf(x0, x1);
        float lse = m + logf(__expf(x0 - m) + __expf(x1 - m));
        out[n * 2 + 0] = x0 - lse;
        out[n * 2 + 1] = x1 - lse;
    }
}

extern "C" void kernel_launch(void* const* d_in, const int* in_sizes, int n_in,
                              void* d_out, int out_size, void* d_ws, size_t ws_size,
                              hipStream_t stream) {
    const float* stat  = (const float*)d_in[0];
    const float* dyn0  = (const float*)d_in[1];
    const float* dyn1  = (const float*)d_in[2];
    const int*   src   = (const int*)d_in[3];
    const int*   trg   = (const int*)d_in[4];
    const float* w0    = (const float*)d_in[5];
    const float* asrc0 = (const float*)d_in[6];
    const float* atrg0 = (const float*)d_in[7];
    const float* w1    = (const float*)d_in[8];
    const float* asrc1 = (const float*)d_in[9];
    const float* atrg1 = (const float*)d_in[10];
    float* out = (float*)d_out;

    const int N = in_sizes[0] / 64;   // 50000
    const int E = in_sizes[3];        // 800000
    const int NBK = (N + 255) >> 8;   // 196 buckets of 256 nodes
    const int CHUNK = (E + NCHUNK - 1) / NCHUNK;
    const int NTILES = (N + 31) >> 5; // 1563

    // ---- workspace layout ----
    float* ws = (float*)d_ws;
    size_t off = 0;
    // hp0h region (N*64 floats = 12.8MB); staging pairs (E int2 = 6.4MB) alias it
    __half2* hp0h = (__half2*)(ws + off);
    int2*    stage = (int2*)(ws + off);
    off += (size_t)N * 64;
    float* s0  = ws + off; off += (size_t)N * 8;
    float* t0  = ws + off; off += (size_t)N * 8;
    float4* pk1 = (float4*)(ws + off); off += (size_t)N * 4;
    float* t1  = ws + off; off += (size_t)N;
    __half2* w2g = (__half2*)(ws + off); off += 8192;   // 32KB packed W
    off = (off + 3) & ~(size_t)3;
    int* iws      = (int*)(ws + off);
    int* rowptr   = iws;                        // NBK*256 + 1
    int* colsrc   = rowptr + NBK * 256 + 1;     // E
    int* H        = colsrc + E;                 // NCHUNK*NBK
    int* basearr  = H + NCHUNK * NBK;           // NCHUNK*NBK
    int* bktstart = basearr + NCHUNK * NBK;     // NBK+1

    // ---- CSR build (tile counting sort, no global atomics) ----
    sort_hist_kernel<<<NCHUNK, 1024, 0, stream>>>(trg, H, E, NBK, CHUNK);
    sort_scan_kernel<<<1, 256, 0, stream>>>(H, basearr, bktstart, rowptr, NBK, NCHUNK, E);
    sort_scatter_kernel<<<NCHUNK, 1024, 0, stream>>>(src, trg, basearr, stage, E, NBK, CHUNK);
    sort_finalize_kernel<<<NBK, 256, 0, stream>>>(stage, bktstart, rowptr, colsrc, NBK);

    // ---- W pre-pack, then LDS-free layer-0 projection + scores ----
    wconv_kernel<<<32, 256, 0, stream>>>(w0, w2g);
    gemm0_kernel<<<NTILES, 256, 0, stream>>>(
        stat, dyn0, dyn1, (const float4*)w2g, asrc0, atrg0, hp0h, s0, t0, N);

    // ---- layer 0 aggregate + ELU + W1 + layer-1 scores (wave per node) ----
    node_accum0_kernel<<<(N + 3) / 4, 256, 0, stream>>>(
        rowptr, colsrc, s0, t0, hp0h, w1, asrc1, atrg1, pk1, t1, N);

    // ---- layer 1 aggregate + mean + log_softmax ----
    node_accum1_kernel<<<(N + 3) / 4, 256, 0, stream>>>(
        rowptr, colsrc, pk1, t1, out, N);
}

// Round 12
// 157.501 us; speedup vs baseline: 1.2672x; 1.1351x over previous
//
#include <hip/hip_runtime.h>
#include <hip/hip_fp16.h>
#include <math.h>

__device__ __forceinline__ float lrelu02(float x) { return x > 0.f ? x : 0.2f * x; }

typedef _Float16 h2_t __attribute__((ext_vector_type(2)));
__device__ __forceinline__ float fdot2(__half2 a, __half2 b, float c) {
    h2_t ha = *reinterpret_cast<h2_t*>(&a);
    h2_t hb = *reinterpret_cast<h2_t*>(&b);
    return __builtin_amdgcn_fdot2(ha, hb, c, false);
}

#define ESHIFT 10.0f   // constant shift replacing global max (alpha is ratio-invariant)
#define NCHUNK 128     // sort chunks (blocks in P1/P3)

// ============ CSR build: tile counting sort, NO global atomics ============
// bucket = trg >> 8 (256 nodes per bucket), nbk = ceil(N/256) <= 256

// P1: per-chunk histogram
__global__ __launch_bounds__(1024) void sort_hist_kernel(
    const int* __restrict__ trg, int* __restrict__ H, int E, int nbk, int chunk)
{
    __shared__ int hist[256];
    int c = blockIdx.x, t = threadIdx.x;
    if (t < 256) hist[t] = 0;
    __syncthreads();
    int e0 = c * chunk, e1 = min(e0 + chunk, E);
    for (int i = e0 + t; i < e1; i += 1024)
        atomicAdd(&hist[trg[i] >> 8], 1);
    __syncthreads();
    if (t < nbk) H[c * nbk + t] = hist[t];
}

// P2: register-prefetched column scan (fix: 128 INDEPENDENT loads up front,
// then pure-register serial scan -> one latency exposure instead of 128)
__global__ __launch_bounds__(256) void sort_scan_kernel(
    const int* __restrict__ H, int* __restrict__ base,
    int* __restrict__ bktstart, int* __restrict__ rowptr,
    int nbk, int E)
{
    __shared__ int sm[256];
    int t = threadIdx.x;
    int hv[NCHUNK];
    int tot = 0;
    if (t < nbk) {
#pragma unroll
        for (int c = 0; c < NCHUNK; ++c) hv[c] = H[c * nbk + t];
#pragma unroll
        for (int c = 0; c < NCHUNK; ++c) tot += hv[c];
    }
    sm[t] = tot;
    __syncthreads();
    for (int off = 1; off < 256; off <<= 1) {
        int x = (t >= off) ? sm[t - off] : 0;
        __syncthreads();
        sm[t] += x;
        __syncthreads();
    }
    int excl = sm[t] - tot;
    if (t < nbk) {
        bktstart[t] = excl;
        int run = excl;
#pragma unroll
        for (int c = 0; c < NCHUNK; ++c) { base[c * nbk + t] = run; run += hv[c]; }
    }
    if (t == 0) { bktstart[nbk] = E; rowptr[nbk * 256] = E; }
}

// P3: scatter (src,trg) pairs bucket-major via LDS cursors (no global atomics)
__global__ __launch_bounds__(1024) void sort_scatter_kernel(
    const int* __restrict__ src, const int* __restrict__ trg,
    const int* __restrict__ base, int2* __restrict__ stage,
    int E, int nbk, int chunk)
{
    __shared__ int cur[256];
    int c = blockIdx.x, t = threadIdx.x;
    if (t < nbk) cur[t] = base[c * nbk + t];
    __syncthreads();
    int e0 = c * chunk, e1 = min(e0 + chunk, E);
    for (int i = e0 + t; i < e1; i += 1024) {
        int tg = trg[i];
        int pos = atomicAdd(&cur[tg >> 8], 1);
        stage[pos] = make_int2(src[i], tg);
    }
}

// P4: one block per bucket: node histogram -> scan -> rowptr + colsrc
__global__ __launch_bounds__(256) void sort_finalize_kernel(
    const int2* __restrict__ stage, const int* __restrict__ bktstart,
    int* __restrict__ rowptr, int* __restrict__ colsrc, int nbk)
{
    __shared__ int hist[256];
    __shared__ int sm[256];
    __shared__ int cur[256];
    int b = blockIdx.x, t = threadIdx.x;
    int s0 = bktstart[b], cnt = bktstart[b + 1] - s0;
    hist[t] = 0;
    __syncthreads();
    for (int i = t; i < cnt; i += 256)
        atomicAdd(&hist[stage[s0 + i].y & 255], 1);
    __syncthreads();
    int h = hist[t];
    sm[t] = h;
    __syncthreads();
    for (int off = 1; off < 256; off <<= 1) {
        int x = (t >= off) ? sm[t - off] : 0;
        __syncthreads();
        sm[t] += x;
        __syncthreads();
    }
    int excl = sm[t] - h;
    cur[t] = s0 + excl;
    rowptr[b * 256 + t] = s0 + excl;
    __syncthreads();
    for (int i = t; i < cnt; i += 256) {
        int2 p = stage[s0 + i];
        int pos = atomicAdd(&cur[p.y & 255], 1);
        colsrc[pos] = p.x;
    }
}

// ---------------- W pre-pack: w2g[f2*128 + c] = half2(w[2f2][c], w[2f2+1][c]) ----
__global__ __launch_bounds__(256) void wconv_kernel(
    const float* __restrict__ w0, __half2* __restrict__ w2g)
{
    int i = blockIdx.x * 256 + threadIdx.x;   // 8192 entries
    if (i >= 8192) return;
    int f2 = i >> 7, c = i & 127;
    int h = c >> 4, o = c & 15;
    float a = w0[h * 2048 + (2 * f2) * 16 + o];
    float b = w0[h * 2048 + (2 * f2 + 1) * 16 + o];
    w2g[i] = __floats2half2_rn(a, b);
}

// ---------------- Layer-0 projection (8 nodes x 4 ch per thread, v_dot2) --------
// No LDS; W read as coalesced/broadcast float4 from 32KB L2-resident w2g.
union F4H { float4 f; __half2 h[4]; };

#define NPT 8   // nodes per thread

__global__ __launch_bounds__(256) void gemm0_kernel(
    const float* __restrict__ stat, const float* __restrict__ dyn0,
    const float* __restrict__ dyn1, const float4* __restrict__ w2g4,
    const float* __restrict__ asrc0, const float* __restrict__ atrg0,
    __half2* __restrict__ hp0h, float* __restrict__ s0, float* __restrict__ t0,
    int n_nodes)
{
    int t = threadIdx.x;
    int cg = t & 31, ns = t >> 5;
    int c0 = cg * 4;
    int h = c0 >> 4, o0 = c0 & 15;
    float4 asv = *reinterpret_cast<const float4*>(&asrc0[h * 16 + o0]);
    float4 atv = *reinterpret_cast<const float4*>(&atrg0[h * 16 + o0]);

    int nb = blockIdx.x * (32 * NPT / 4) + ns * NPT;
    int nn[NPT], nc[NPT];
#pragma unroll
    for (int i = 0; i < NPT; ++i) { nn[i] = nb + i; nc[i] = min(nn[i], n_nodes - 1); }

    float acc[NPT][4];
#pragma unroll
    for (int i = 0; i < NPT; ++i)
#pragma unroll
        for (int j = 0; j < 4; ++j) acc[i][j] = 0.f;

#define SEG(PTR, FDIM, FQN, F2BASE)                                              \
    _Pragma("unroll 2")                                                          \
    for (int fq = 0; fq < FQN; ++fq) {                                           \
        __half2 eh[NPT][2];                                                      \
        _Pragma("unroll")                                                        \
        for (int i = 0; i < NPT; ++i) {                                          \
            float4 v = *reinterpret_cast<const float4*>(&PTR[(size_t)nc[i] * FDIM + fq * 4]); \
            eh[i][0] = __floats2half2_rn(v.x, v.y);                              \
            eh[i][1] = __floats2half2_rn(v.z, v.w);                              \
        }                                                                        \
        _Pragma("unroll")                                                        \
        for (int p = 0; p < 2; ++p) {                                            \
            F4H wu; wu.f = w2g4[(F2BASE + fq * 2 + p) * 32 + cg];                \
            _Pragma("unroll")                                                    \
            for (int i = 0; i < NPT; ++i) {                                      \
                acc[i][0] = fdot2(eh[i][p], wu.h[0], acc[i][0]);                 \
                acc[i][1] = fdot2(eh[i][p], wu.h[1], acc[i][1]);                 \
                acc[i][2] = fdot2(eh[i][p], wu.h[2], acc[i][2]);                 \
                acc[i][3] = fdot2(eh[i][p], wu.h[3], acc[i][3]);                 \
            }                                                                    \
        }                                                                        \
    }

    SEG(dyn0, 32, 8, 0)
    SEG(dyn1, 32, 8, 16)
    SEG(stat, 64, 16, 32)
#undef SEG

#pragma unroll
    for (int i = 0; i < NPT; ++i) {
        bool valid = nn[i] < n_nodes;
        if (valid) {
            hp0h[(size_t)nn[i] * 64 + (c0 >> 1)]     = __floats2half2_rn(acc[i][0], acc[i][1]);
            hp0h[(size_t)nn[i] * 64 + (c0 >> 1) + 1] = __floats2half2_rn(acc[i][2], acc[i][3]);
        }
        float ps = acc[i][0] * asv.x + acc[i][1] * asv.y + acc[i][2] * asv.z + acc[i][3] * asv.w;
        float pt = acc[i][0] * atv.x + acc[i][1] * atv.y + acc[i][2] * atv.z + acc[i][3] * atv.w;
        ps += __shfl_xor(ps, 1); ps += __shfl_xor(ps, 2);
        pt += __shfl_xor(pt, 1); pt += __shfl_xor(pt, 2);
        if ((cg & 3) == 0 && valid) {
            s0[nn[i] * 8 + h] = ps;
            t0[nn[i] * 8 + h] = pt;
        }
    }
}

// ---------------- Layer-0 aggregate: one WAVE per target node ----------------
#define CH 64
__global__ __launch_bounds__(256) void node_accum0_kernel(
    const int* __restrict__ rowptr, const int* __restrict__ colsrc,
    const float* __restrict__ s0, const float* __restrict__ t0,
    const __half2* __restrict__ hp0h, const float* __restrict__ w1,
    const float* __restrict__ asrc1, const float* __restrict__ atrg1,
    float4* __restrict__ pk1, float* __restrict__ t1, int n_nodes)
{
    __shared__ int   se_s[4][CH];
    __shared__ float p_s[4][CH * 8];

    int w = threadIdx.x >> 6;
    int l = threadIdx.x & 63;
    int n = blockIdx.x * 4 + w;
    if (n >= n_nodes) return;

    int start = rowptr[n];
    int deg = rowptr[n + 1] - start;
    int hl = l & 7;          // head for p-compute
    int hc = l >> 3;         // head of my channels
    float tval = t0[n * 8 + hl];
    const float* pw = p_s[w];

    float acc0 = 0.f, acc1 = 0.f, dsum = 0.f;
    for (int chunk = 0; chunk < deg; chunk += CH) {
        int m = min(CH, deg - chunk);
        if (l < m) se_s[w][l] = colsrc[start + chunk + l];
        __builtin_amdgcn_wave_barrier();
        int iters = (m + 7) >> 3;
        for (int r = 0; r < iters; ++r) {
            int e = r * 8 + (l >> 3);
            float p = 0.f;
            if (e < m) {
                int se = se_s[w][e];
                float x = s0[se * 8 + hl] + tval;
                p = __expf(lrelu02(x) - ESHIFT);
            }
            p_s[w][r * 64 + l] = p;   // == p_s[e*8 + hl]
            dsum += p;
        }
        __builtin_amdgcn_wave_barrier();
        int e = 0;
        for (; e + 4 <= m; e += 4) {
            int sa = se_s[w][e + 0], sb = se_s[w][e + 1];
            int sc = se_s[w][e + 2], sd = se_s[w][e + 3];
            float2 fa = __half22float2(hp0h[(size_t)sa * 64 + l]);
            float2 fb = __half22float2(hp0h[(size_t)sb * 64 + l]);
            float2 fc = __half22float2(hp0h[(size_t)sc * 64 + l]);
            float2 fd = __half22float2(hp0h[(size_t)sd * 64 + l]);
            float pa = pw[(e + 0) * 8 + hc], pb = pw[(e + 1) * 8 + hc];
            float pc2 = pw[(e + 2) * 8 + hc], pd = pw[(e + 3) * 8 + hc];
            acc0 += fa.x * pa; acc1 += fa.y * pa;
            acc0 += fb.x * pb; acc1 += fb.y * pb;
            acc0 += fc.x * pc2; acc1 += fc.y * pc2;
            acc0 += fd.x * pd; acc1 += fd.y * pd;
        }
        for (; e < m; ++e) {
            int sa = se_s[w][e];
            float2 fa = __half22float2(hp0h[(size_t)sa * 64 + l]);
            float pa = pw[e * 8 + hc];
            acc0 += fa.x * pa; acc1 += fa.y * pa;
        }
        __builtin_amdgcn_wave_barrier();
    }

    dsum += __shfl_xor(dsum, 8);
    dsum += __shfl_xor(dsum, 16);
    dsum += __shfl_xor(dsum, 32);
    float denom = __shfl(dsum, hc);
    float inv = 1.f / (denom + 1e-16f);
    float v0 = acc0 * inv; v0 = v0 > 0.f ? v0 : expm1f(v0);
    float v1 = acc1 * inv; v1 = v1 > 0.f ? v1 : expm1f(v1);

    float4 wv = *reinterpret_cast<const float4*>(&w1[l * 4]);
    float r0 = v0 * wv.x + v1 * wv.z;
    float r1 = v0 * wv.y + v1 * wv.w;
#pragma unroll
    for (int off = 32; off > 0; off >>= 1) {
        r0 += __shfl_down(r0, off);
        r1 += __shfl_down(r1, off);
    }
    if (l == 0) {
        float s1v = r0 * asrc1[0] + r1 * asrc1[1];
        float t1v = r0 * atrg1[0] + r1 * atrg1[1];
        float4 pk; pk.x = r0; pk.y = r1; pk.z = s1v; pk.w = 0.f;
        pk1[n] = pk;
        t1[n] = t1v;
    }
}

// ---------------- Layer-1 aggregate + mean + log_softmax -> out ----------------
__global__ __launch_bounds__(256) void node_accum1_kernel(
    const int* __restrict__ rowptr, const int* __restrict__ colsrc,
    const float4* __restrict__ pk1, const float* __restrict__ t1,
    float* __restrict__ out, int n_nodes)
{
    int lane = threadIdx.x & 63;
    int n = blockIdx.x * 4 + (threadIdx.x >> 6);
    if (n >= n_nodes) return;
    int start = rowptr[n], deg = rowptr[n + 1] - start;
    float tn = t1[n];
    float d = 0.f, a0 = 0.f, a1 = 0.f;
    for (int i = lane; i < deg; i += 64) {
        int se = colsrc[start + i];
        float4 q = pk1[se];
        float p = __expf(lrelu02(q.z + tn) - ESHIFT);
        d += p;
        a0 += p * q.x;
        a1 += p * q.y;
    }
#pragma unroll
    for (int off = 32; off > 0; off >>= 1) {
        d  += __shfl_down(d, off);
        a0 += __shfl_down(a0, off);
        a1 += __shfl_down(a1, off);
    }
    if (lane == 0) {
        float inv = 1.f / (d + 1e-16f);
        float x0 = a0 * inv, x1 = a1 * inv;
        float m = fmaxf(x0, x1);
        float lse = m + logf(__expf(x0 - m) + __expf(x1 - m));
        out[n * 2 + 0] = x0 - lse;
        out[n * 2 + 1] = x1 - lse;
    }
}

extern "C" void kernel_launch(void* const* d_in, const int* in_sizes, int n_in,
                              void* d_out, int out_size, void* d_ws, size_t ws_size,
                              hipStream_t stream) {
    const float* stat  = (const float*)d_in[0];
    const float* dyn0  = (const float*)d_in[1];
    const float* dyn1  = (const float*)d_in[2];
    const int*   src   = (const int*)d_in[3];
    const int*   trg   = (const int*)d_in[4];
    const float* w0    = (const float*)d_in[5];
    const float* asrc0 = (const float*)d_in[6];
    const float* atrg0 = (const float*)d_in[7];
    const float* w1    = (const float*)d_in[8];
    const float* asrc1 = (const float*)d_in[9];
    const float* atrg1 = (const float*)d_in[10];
    float* out = (float*)d_out;

    const int N = in_sizes[0] / 64;   // 50000
    const int E = in_sizes[3];        // 800000
    const int NBK = (N + 255) >> 8;   // 196 buckets of 256 nodes
    const int CHUNK = (E + NCHUNK - 1) / NCHUNK;
    const int NT64 = (N + 63) >> 6;   // 782 blocks of 64 nodes

    // ---- workspace layout ----
    float* ws = (float*)d_ws;
    size_t off = 0;
    // hp0h region (N*64 floats = 12.8MB); staging pairs (E int2 = 6.4MB) alias it
    __half2* hp0h = (__half2*)(ws + off);
    int2*    stage = (int2*)(ws + off);
    off += (size_t)N * 64;
    float* s0  = ws + off; off += (size_t)N * 8;
    float* t0  = ws + off; off += (size_t)N * 8;
    float4* pk1 = (float4*)(ws + off); off += (size_t)N * 4;
    float* t1  = ws + off; off += (size_t)N;
    __half2* w2g = (__half2*)(ws + off); off += 8192;   // 32KB packed W
    off = (off + 3) & ~(size_t)3;
    int* iws      = (int*)(ws + off);
    int* rowptr   = iws;                        // NBK*256 + 1
    int* colsrc   = rowptr + NBK * 256 + 1;     // E
    int* H        = colsrc + E;                 // NCHUNK*NBK
    int* basearr  = H + NCHUNK * NBK;           // NCHUNK*NBK
    int* bktstart = basearr + NCHUNK * NBK;     // NBK+1

    // ---- CSR build (tile counting sort, no global atomics) ----
    sort_hist_kernel<<<NCHUNK, 1024, 0, stream>>>(trg, H, E, NBK, CHUNK);
    sort_scan_kernel<<<1, 256, 0, stream>>>(H, basearr, bktstart, rowptr, NBK, E);
    sort_scatter_kernel<<<NCHUNK, 1024, 0, stream>>>(src, trg, basearr, stage, E, NBK, CHUNK);
    sort_finalize_kernel<<<NBK, 256, 0, stream>>>(stage, bktstart, rowptr, colsrc, NBK);

    // ---- W pre-pack, then LDS-free layer-0 projection + scores ----
    wconv_kernel<<<32, 256, 0, stream>>>(w0, w2g);
    gemm0_kernel<<<NT64, 256, 0, stream>>>(
        stat, dyn0, dyn1, (const float4*)w2g, asrc0, atrg0, hp0h, s0, t0, N);

    // ---- layer 0 aggregate + ELU + W1 + layer-1 scores (wave per node) ----
    node_accum0_kernel<<<(N + 3) / 4, 256, 0, stream>>>(
        rowptr, colsrc, s0, t0, hp0h, w1, asrc1, atrg1, pk1, t1, N);

    // ---- layer 1 aggregate + mean + log_softmax ----
    node_accum1_kernel<<<(N + 3) / 4, 256, 0, stream>>>(
        rowptr, colsrc, pk1, t1, out, N);
}

// Round 13
// 145.476 us; speedup vs baseline: 1.3719x; 1.0827x over previous
//
#include <hip/hip_runtime.h>
#include <hip/hip_fp16.h>
#include <math.h>

__device__ __forceinline__ float lrelu02(float x) { return x > 0.f ? x : 0.2f * x; }

typedef _Float16 h2_t __attribute__((ext_vector_type(2)));
__device__ __forceinline__ float fdot2(__half2 a, __half2 b, float c) {
    h2_t ha = *reinterpret_cast<h2_t*>(&a);
    h2_t hb = *reinterpret_cast<h2_t*>(&b);
    return __builtin_amdgcn_fdot2(ha, hb, c, false);
}

#define ESHIFT 10.0f   // constant shift replacing global max (alpha is ratio-invariant)
#define NCHUNK 128     // sort chunks (blocks in P1/P3)

// ============ CSR build: tile counting sort, NO global atomics ============
// bucket = trg >> 8 (256 nodes per bucket), nbk = ceil(N/256) <= 256

// P1: per-chunk histogram
__global__ __launch_bounds__(1024) void sort_hist_kernel(
    const int* __restrict__ trg, int* __restrict__ H, int E, int nbk, int chunk)
{
    __shared__ int hist[256];
    int c = blockIdx.x, t = threadIdx.x;
    if (t < 256) hist[t] = 0;
    __syncthreads();
    int e0 = c * chunk, e1 = min(e0 + chunk, E);
    for (int i = e0 + t; i < e1; i += 1024)
        atomicAdd(&hist[trg[i] >> 8], 1);
    __syncthreads();
    if (t < nbk) H[c * nbk + t] = hist[t];
}

// P2: register-prefetched column scan (128 independent loads up front)
__global__ __launch_bounds__(256) void sort_scan_kernel(
    const int* __restrict__ H, int* __restrict__ base,
    int* __restrict__ bktstart, int* __restrict__ rowptr,
    int nbk, int E)
{
    __shared__ int sm[256];
    int t = threadIdx.x;
    int hv[NCHUNK];
    int tot = 0;
    if (t < nbk) {
#pragma unroll
        for (int c = 0; c < NCHUNK; ++c) hv[c] = H[c * nbk + t];
#pragma unroll
        for (int c = 0; c < NCHUNK; ++c) tot += hv[c];
    }
    sm[t] = tot;
    __syncthreads();
    for (int off = 1; off < 256; off <<= 1) {
        int x = (t >= off) ? sm[t - off] : 0;
        __syncthreads();
        sm[t] += x;
        __syncthreads();
    }
    int excl = sm[t] - tot;
    if (t < nbk) {
        bktstart[t] = excl;
        int run = excl;
#pragma unroll
        for (int c = 0; c < NCHUNK; ++c) { base[c * nbk + t] = run; run += hv[c]; }
    }
    if (t == 0) { bktstart[nbk] = E; rowptr[nbk * 256] = E; }
}

// P3: scatter (src,trg) pairs bucket-major via LDS cursors (no global atomics)
__global__ __launch_bounds__(1024) void sort_scatter_kernel(
    const int* __restrict__ src, const int* __restrict__ trg,
    const int* __restrict__ base, int2* __restrict__ stage,
    int E, int nbk, int chunk)
{
    __shared__ int cur[256];
    int c = blockIdx.x, t = threadIdx.x;
    if (t < nbk) cur[t] = base[c * nbk + t];
    __syncthreads();
    int e0 = c * chunk, e1 = min(e0 + chunk, E);
    for (int i = e0 + t; i < e1; i += 1024) {
        int tg = trg[i];
        int pos = atomicAdd(&cur[tg >> 8], 1);
        stage[pos] = make_int2(src[i], tg);
    }
}

// P4: one block per bucket: node histogram -> scan -> rowptr + colsrc
__global__ __launch_bounds__(256) void sort_finalize_kernel(
    const int2* __restrict__ stage, const int* __restrict__ bktstart,
    int* __restrict__ rowptr, int* __restrict__ colsrc, int nbk)
{
    __shared__ int hist[256];
    __shared__ int sm[256];
    __shared__ int cur[256];
    int b = blockIdx.x, t = threadIdx.x;
    int s0 = bktstart[b], cnt = bktstart[b + 1] - s0;
    hist[t] = 0;
    __syncthreads();
    for (int i = t; i < cnt; i += 256)
        atomicAdd(&hist[stage[s0 + i].y & 255], 1);
    __syncthreads();
    int h = hist[t];
    sm[t] = h;
    __syncthreads();
    for (int off = 1; off < 256; off <<= 1) {
        int x = (t >= off) ? sm[t - off] : 0;
        __syncthreads();
        sm[t] += x;
        __syncthreads();
    }
    int excl = sm[t] - h;
    cur[t] = s0 + excl;
    rowptr[b * 256 + t] = s0 + excl;
    __syncthreads();
    for (int i = t; i < cnt; i += 256) {
        int2 p = stage[s0 + i];
        int pos = atomicAdd(&cur[p.y & 255], 1);
        colsrc[pos] = p.x;
    }
}

// ---------------- W pre-pack: w2g[f2*128 + c] = half2(w[2f2][c], w[2f2+1][c]) ----
__global__ __launch_bounds__(256) void wconv_kernel(
    const float* __restrict__ w0, __half2* __restrict__ w2g)
{
    int i = blockIdx.x * 256 + threadIdx.x;   // 8192 entries
    if (i >= 8192) return;
    int f2 = i >> 7, c = i & 127;
    int h = c >> 4, o = c & 15;
    float a = w0[h * 2048 + (2 * f2) * 16 + o];
    float b = w0[h * 2048 + (2 * f2 + 1) * 16 + o];
    w2g[i] = __floats2half2_rn(a, b);
}

// ---------------- Layer-0 projection (2 nodes x 4 ch per thread, v_dot2) --------
// No LDS; W from 32KB L1-resident w2g. NPT=2: maximize total wave count
// (25K waves -> 12/SIMD) since gemm0 is wave-starved, not ILP-starved.
union F4H { float4 f; __half2 h[4]; };

#define NPT 2   // nodes per thread

__global__ __launch_bounds__(256) void gemm0_kernel(
    const float* __restrict__ stat, const float* __restrict__ dyn0,
    const float* __restrict__ dyn1, const float4* __restrict__ w2g4,
    const float* __restrict__ asrc0, const float* __restrict__ atrg0,
    __half2* __restrict__ hp0h, float* __restrict__ s0, float* __restrict__ t0,
    int n_nodes)
{
    int t = threadIdx.x;
    int cg = t & 31, ns = t >> 5;
    int c0 = cg * 4;
    int h = c0 >> 4, o0 = c0 & 15;
    float4 asv = *reinterpret_cast<const float4*>(&asrc0[h * 16 + o0]);
    float4 atv = *reinterpret_cast<const float4*>(&atrg0[h * 16 + o0]);

    int nb = blockIdx.x * (8 * NPT) + ns * NPT;
    int nn[NPT], nc[NPT];
#pragma unroll
    for (int i = 0; i < NPT; ++i) { nn[i] = nb + i; nc[i] = min(nn[i], n_nodes - 1); }

    float acc[NPT][4];
#pragma unroll
    for (int i = 0; i < NPT; ++i)
#pragma unroll
        for (int j = 0; j < 4; ++j) acc[i][j] = 0.f;

#define SEG(PTR, FDIM, FQN, F2BASE)                                              \
    _Pragma("unroll 2")                                                          \
    for (int fq = 0; fq < FQN; ++fq) {                                           \
        __half2 eh[NPT][2];                                                      \
        _Pragma("unroll")                                                        \
        for (int i = 0; i < NPT; ++i) {                                          \
            float4 v = *reinterpret_cast<const float4*>(&PTR[(size_t)nc[i] * FDIM + fq * 4]); \
            eh[i][0] = __floats2half2_rn(v.x, v.y);                              \
            eh[i][1] = __floats2half2_rn(v.z, v.w);                              \
        }                                                                        \
        _Pragma("unroll")                                                        \
        for (int p = 0; p < 2; ++p) {                                            \
            F4H wu; wu.f = w2g4[(F2BASE + fq * 2 + p) * 32 + cg];                \
            _Pragma("unroll")                                                    \
            for (int i = 0; i < NPT; ++i) {                                      \
                acc[i][0] = fdot2(eh[i][p], wu.h[0], acc[i][0]);                 \
                acc[i][1] = fdot2(eh[i][p], wu.h[1], acc[i][1]);                 \
                acc[i][2] = fdot2(eh[i][p], wu.h[2], acc[i][2]);                 \
                acc[i][3] = fdot2(eh[i][p], wu.h[3], acc[i][3]);                 \
            }                                                                    \
        }                                                                        \
    }

    SEG(dyn0, 32, 8, 0)
    SEG(dyn1, 32, 8, 16)
    SEG(stat, 64, 16, 32)
#undef SEG

#pragma unroll
    for (int i = 0; i < NPT; ++i) {
        bool valid = nn[i] < n_nodes;
        if (valid) {
            hp0h[(size_t)nn[i] * 64 + (c0 >> 1)]     = __floats2half2_rn(acc[i][0], acc[i][1]);
            hp0h[(size_t)nn[i] * 64 + (c0 >> 1) + 1] = __floats2half2_rn(acc[i][2], acc[i][3]);
        }
        float ps = acc[i][0] * asv.x + acc[i][1] * asv.y + acc[i][2] * asv.z + acc[i][3] * asv.w;
        float pt = acc[i][0] * atv.x + acc[i][1] * atv.y + acc[i][2] * atv.z + acc[i][3] * atv.w;
        ps += __shfl_xor(ps, 1); ps += __shfl_xor(ps, 2);
        pt += __shfl_xor(pt, 1); pt += __shfl_xor(pt, 2);
        if ((cg & 3) == 0 && valid) {
            s0[nn[i] * 8 + h] = ps;
            t0[nn[i] * 8 + h] = pt;
        }
    }
}

// ---------------- Layer-0 aggregate: one WAVE per target node ----------------
#define CH 64
__global__ __launch_bounds__(256) void node_accum0_kernel(
    const int* __restrict__ rowptr, const int* __restrict__ colsrc,
    const float* __restrict__ s0, const float* __restrict__ t0,
    const __half2* __restrict__ hp0h, const float* __restrict__ w1,
    const float* __restrict__ asrc1, const float* __restrict__ atrg1,
    float4* __restrict__ pk1, float* __restrict__ t1, int n_nodes)
{
    __shared__ int   se_s[4][CH];
    __shared__ float p_s[4][CH * 8];

    int w = threadIdx.x >> 6;
    int l = threadIdx.x & 63;
    int n = blockIdx.x * 4 + w;
    if (n >= n_nodes) return;

    int start = rowptr[n];
    int deg = rowptr[n + 1] - start;
    int hl = l & 7;          // head for p-compute
    int hc = l >> 3;         // head of my channels
    float tval = t0[n * 8 + hl];
    const float* pw = p_s[w];

    float acc0 = 0.f, acc1 = 0.f, dsum = 0.f;
    for (int chunk = 0; chunk < deg; chunk += CH) {
        int m = min(CH, deg - chunk);
        if (l < m) se_s[w][l] = colsrc[start + chunk + l];
        __builtin_amdgcn_wave_barrier();
        int iters = (m + 7) >> 3;
        for (int r = 0; r < iters; ++r) {
            int e = r * 8 + (l >> 3);
            float p = 0.f;
            if (e < m) {
                int se = se_s[w][e];
                float x = s0[se * 8 + hl] + tval;
                p = __expf(lrelu02(x) - ESHIFT);
            }
            p_s[w][r * 64 + l] = p;   // == p_s[e*8 + hl]
            dsum += p;
        }
        __builtin_amdgcn_wave_barrier();
        int e = 0;
        for (; e + 4 <= m; e += 4) {
            int sa = se_s[w][e + 0], sb = se_s[w][e + 1];
            int sc = se_s[w][e + 2], sd = se_s[w][e + 3];
            float2 fa = __half22float2(hp0h[(size_t)sa * 64 + l]);
            float2 fb = __half22float2(hp0h[(size_t)sb * 64 + l]);
            float2 fc = __half22float2(hp0h[(size_t)sc * 64 + l]);
            float2 fd = __half22float2(hp0h[(size_t)sd * 64 + l]);
            float pa = pw[(e + 0) * 8 + hc], pb = pw[(e + 1) * 8 + hc];
            float pc2 = pw[(e + 2) * 8 + hc], pd = pw[(e + 3) * 8 + hc];
            acc0 += fa.x * pa; acc1 += fa.y * pa;
            acc0 += fb.x * pb; acc1 += fb.y * pb;
            acc0 += fc.x * pc2; acc1 += fc.y * pc2;
            acc0 += fd.x * pd; acc1 += fd.y * pd;
        }
        for (; e < m; ++e) {
            int sa = se_s[w][e];
            float2 fa = __half22float2(hp0h[(size_t)sa * 64 + l]);
            float pa = pw[e * 8 + hc];
            acc0 += fa.x * pa; acc1 += fa.y * pa;
        }
        __builtin_amdgcn_wave_barrier();
    }

    dsum += __shfl_xor(dsum, 8);
    dsum += __shfl_xor(dsum, 16);
    dsum += __shfl_xor(dsum, 32);
    float denom = __shfl(dsum, hc);
    float inv = 1.f / (denom + 1e-16f);
    float v0 = acc0 * inv; v0 = v0 > 0.f ? v0 : expm1f(v0);
    float v1 = acc1 * inv; v1 = v1 > 0.f ? v1 : expm1f(v1);

    float4 wv = *reinterpret_cast<const float4*>(&w1[l * 4]);
    float r0 = v0 * wv.x + v1 * wv.z;
    float r1 = v0 * wv.y + v1 * wv.w;
#pragma unroll
    for (int off = 32; off > 0; off >>= 1) {
        r0 += __shfl_down(r0, off);
        r1 += __shfl_down(r1, off);
    }
    if (l == 0) {
        float s1v = r0 * asrc1[0] + r1 * asrc1[1];
        float t1v = r0 * atrg1[0] + r1 * atrg1[1];
        float4 pk; pk.x = r0; pk.y = r1; pk.z = s1v; pk.w = 0.f;
        pk1[n] = pk;
        t1[n] = t1v;
    }
}

// ---------------- Layer-1 aggregate + mean + log_softmax -> out ----------------
__global__ __launch_bounds__(256) void node_accum1_kernel(
    const int* __restrict__ rowptr, const int* __restrict__ colsrc,
    const float4* __restrict__ pk1, const float* __restrict__ t1,
    float* __restrict__ out, int n_nodes)
{
    int lane = threadIdx.x & 63;
    int n = blockIdx.x * 4 + (threadIdx.x >> 6);
    if (n >= n_nodes) return;
    int start = rowptr[n], deg = rowptr[n + 1] - start;
    float tn = t1[n];
    float d = 0.f, a0 = 0.f, a1 = 0.f;
    for (int i = lane; i < deg; i += 64) {
        int se = colsrc[start + i];
        float4 q = pk1[se];
        float p = __expf(lrelu02(q.z + tn) - ESHIFT);
        d += p;
        a0 += p * q.x;
        a1 += p * q.y;
    }
#pragma unroll
    for (int off = 32; off > 0; off >>= 1) {
        d  += __shfl_down(d, off);
        a0 += __shfl_down(a0, off);
        a1 += __shfl_down(a1, off);
    }
    if (lane == 0) {
        float inv = 1.f / (d + 1e-16f);
        float x0 = a0 * inv, x1 = a1 * inv;
        float m = fmaxf(x0, x1);
        float lse = m + logf(__expf(x0 - m) + __expf(x1 - m));
        out[n * 2 + 0] = x0 - lse;
        out[n * 2 + 1] = x1 - lse;
    }
}

extern "C" void kernel_launch(void* const* d_in, const int* in_sizes, int n_in,
                              void* d_out, int out_size, void* d_ws, size_t ws_size,
                              hipStream_t stream) {
    const float* stat  = (const float*)d_in[0];
    const float* dyn0  = (const float*)d_in[1];
    const float* dyn1  = (const float*)d_in[2];
    const int*   src   = (const int*)d_in[3];
    const int*   trg   = (const int*)d_in[4];
    const float* w0    = (const float*)d_in[5];
    const float* asrc0 = (const float*)d_in[6];
    const float* atrg0 = (const float*)d_in[7];
    const float* w1    = (const float*)d_in[8];
    const float* asrc1 = (const float*)d_in[9];
    const float* atrg1 = (const float*)d_in[10];
    float* out = (float*)d_out;

    const int N = in_sizes[0] / 64;   // 50000
    const int E = in_sizes[3];        // 800000
    const int NBK = (N + 255) >> 8;   // 196 buckets of 256 nodes
    const int CHUNK = (E + NCHUNK - 1) / NCHUNK;
    const int NPB = 8 * NPT;          // nodes per block (16)
    const int NTB = (N + NPB - 1) / NPB;  // 3125 blocks

    // ---- workspace layout ----
    float* ws = (float*)d_ws;
    size_t off = 0;
    // hp0h region (N*64 floats = 12.8MB); staging pairs (E int2 = 6.4MB) alias it
    __half2* hp0h = (__half2*)(ws + off);
    int2*    stage = (int2*)(ws + off);
    off += (size_t)N * 64;
    float* s0  = ws + off; off += (size_t)N * 8;
    float* t0  = ws + off; off += (size_t)N * 8;
    float4* pk1 = (float4*)(ws + off); off += (size_t)N * 4;
    float* t1  = ws + off; off += (size_t)N;
    __half2* w2g = (__half2*)(ws + off); off += 8192;   // 32KB packed W
    off = (off + 3) & ~(size_t)3;
    int* iws      = (int*)(ws + off);
    int* rowptr   = iws;                        // NBK*256 + 1
    int* colsrc   = rowptr + NBK * 256 + 1;     // E
    int* H        = colsrc + E;                 // NCHUNK*NBK
    int* basearr  = H + NCHUNK * NBK;           // NCHUNK*NBK
    int* bktstart = basearr + NCHUNK * NBK;     // NBK+1

    // ---- CSR build (tile counting sort, no global atomics) ----
    sort_hist_kernel<<<NCHUNK, 1024, 0, stream>>>(trg, H, E, NBK, CHUNK);
    sort_scan_kernel<<<1, 256, 0, stream>>>(H, basearr, bktstart, rowptr, NBK, E);
    sort_scatter_kernel<<<NCHUNK, 1024, 0, stream>>>(src, trg, basearr, stage, E, NBK, CHUNK);
    sort_finalize_kernel<<<NBK, 256, 0, stream>>>(stage, bktstart, rowptr, colsrc, NBK);

    // ---- W pre-pack, then LDS-free layer-0 projection + scores ----
    wconv_kernel<<<32, 256, 0, stream>>>(w0, w2g);
    gemm0_kernel<<<NTB, 256, 0, stream>>>(
        stat, dyn0, dyn1, (const float4*)w2g, asrc0, atrg0, hp0h, s0, t0, N);

    // ---- layer 0 aggregate + ELU + W1 + layer-1 scores (wave per node) ----
    node_accum0_kernel<<<(N + 3) / 4, 256, 0, stream>>>(
        rowptr, colsrc, s0, t0, hp0h, w1, asrc1, atrg1, pk1, t1, N);

    // ---- layer 1 aggregate + mean + log_softmax ----
    node_accum1_kernel<<<(N + 3) / 4, 256, 0, stream>>>(
        rowptr, colsrc, pk1, t1, out, N);
}

// Round 14
// 129.039 us; speedup vs baseline: 1.5466x; 1.1274x over previous
//
#include <hip/hip_runtime.h>
#include <hip/hip_fp16.h>
#include <math.h>

__device__ __forceinline__ float lrelu02(float x) { return x > 0.f ? x : 0.2f * x; }

typedef _Float16 h2_t __attribute__((ext_vector_type(2)));
__device__ __forceinline__ float fdot2(__half2 a, __half2 b, float c) {
    h2_t ha = *reinterpret_cast<h2_t*>(&a);
    h2_t hb = *reinterpret_cast<h2_t*>(&b);
    return __builtin_amdgcn_fdot2(ha, hb, c, false);
}

#define ESHIFT 10.0f   // constant shift replacing global max (alpha is ratio-invariant)
#define NCHUNK 128     // sort chunks (blocks in P1/P3)

// ============ CSR build: tile counting sort, NO global atomics ============
// bucket = trg >> 8 (256 nodes per bucket), nbk = ceil(N/256) <= 256

// P1: per-chunk histogram
__global__ __launch_bounds__(1024) void sort_hist_kernel(
    const int* __restrict__ trg, int* __restrict__ H, int E, int nbk, int chunk)
{
    __shared__ int hist[256];
    int c = blockIdx.x, t = threadIdx.x;
    if (t < 256) hist[t] = 0;
    __syncthreads();
    int e0 = c * chunk, e1 = min(e0 + chunk, E);
    for (int i = e0 + t; i < e1; i += 1024)
        atomicAdd(&hist[trg[i] >> 8], 1);
    __syncthreads();
    if (t < nbk) H[c * nbk + t] = hist[t];
}

// P2: register-prefetched column scan (128 independent loads up front)
__global__ __launch_bounds__(256) void sort_scan_kernel(
    const int* __restrict__ H, int* __restrict__ base,
    int* __restrict__ bktstart, int* __restrict__ rowptr,
    int nbk, int E)
{
    __shared__ int sm[256];
    int t = threadIdx.x;
    int hv[NCHUNK];
    int tot = 0;
    if (t < nbk) {
#pragma unroll
        for (int c = 0; c < NCHUNK; ++c) hv[c] = H[c * nbk + t];
#pragma unroll
        for (int c = 0; c < NCHUNK; ++c) tot += hv[c];
    }
    sm[t] = tot;
    __syncthreads();
    for (int off = 1; off < 256; off <<= 1) {
        int x = (t >= off) ? sm[t - off] : 0;
        __syncthreads();
        sm[t] += x;
        __syncthreads();
    }
    int excl = sm[t] - tot;
    if (t < nbk) {
        bktstart[t] = excl;
        int run = excl;
#pragma unroll
        for (int c = 0; c < NCHUNK; ++c) { base[c * nbk + t] = run; run += hv[c]; }
    }
    if (t == 0) { bktstart[nbk] = E; rowptr[nbk * 256] = E; }
}

// P3: scatter (src,trg) pairs bucket-major via LDS cursors (no global atomics)
__global__ __launch_bounds__(1024) void sort_scatter_kernel(
    const int* __restrict__ src, const int* __restrict__ trg,
    const int* __restrict__ base, int2* __restrict__ stage,
    int E, int nbk, int chunk)
{
    __shared__ int cur[256];
    int c = blockIdx.x, t = threadIdx.x;
    if (t < nbk) cur[t] = base[c * nbk + t];
    __syncthreads();
    int e0 = c * chunk, e1 = min(e0 + chunk, E);
    for (int i = e0 + t; i < e1; i += 1024) {
        int tg = trg[i];
        int pos = atomicAdd(&cur[tg >> 8], 1);
        stage[pos] = make_int2(src[i], tg);
    }
}

// P4: one block per bucket: node histogram -> scan -> rowptr + colsrc
__global__ __launch_bounds__(256) void sort_finalize_kernel(
    const int2* __restrict__ stage, const int* __restrict__ bktstart,
    int* __restrict__ rowptr, int* __restrict__ colsrc, int nbk)
{
    __shared__ int hist[256];
    __shared__ int sm[256];
    __shared__ int cur[256];
    int b = blockIdx.x, t = threadIdx.x;
    int s0 = bktstart[b], cnt = bktstart[b + 1] - s0;
    hist[t] = 0;
    __syncthreads();
    for (int i = t; i < cnt; i += 256)
        atomicAdd(&hist[stage[s0 + i].y & 255], 1);
    __syncthreads();
    int h = hist[t];
    sm[t] = h;
    __syncthreads();
    for (int off = 1; off < 256; off <<= 1) {
        int x = (t >= off) ? sm[t - off] : 0;
        __syncthreads();
        sm[t] += x;
        __syncthreads();
    }
    int excl = sm[t] - h;
    cur[t] = s0 + excl;
    rowptr[b * 256 + t] = s0 + excl;
    __syncthreads();
    for (int i = t; i < cnt; i += 256) {
        int2 p = stage[s0 + i];
        int pos = atomicAdd(&cur[p.y & 255], 1);
        colsrc[pos] = p.x;
    }
}

// ---------------- W pre-pack: w2g[f2*128 + c] = half2(w[2f2][c], w[2f2+1][c]) ----
__global__ __launch_bounds__(256) void wconv_kernel(
    const float* __restrict__ w0, __half2* __restrict__ w2g)
{
    int i = blockIdx.x * 256 + threadIdx.x;   // 8192 entries
    if (i >= 8192) return;
    int f2 = i >> 7, c = i & 127;
    int h = c >> 4, o = c & 15;
    float a = w0[h * 2048 + (2 * f2) * 16 + o];
    float b = w0[h * 2048 + (2 * f2 + 1) * 16 + o];
    w2g[i] = __floats2half2_rn(a, b);
}

// ---------------- Layer-0 projection (2 nodes x 4 ch per thread, v_dot2) --------
// W staged in LDS (32KB): global loads drop to emb-only; W stream moves to the
// LDS pipe (ds_read_b128), overlapping VMEM/LDS/VALU. NPT=2 keeps 25K waves.
union F4H { float4 f; __half2 h[4]; };

#define NPT 2   // nodes per thread

__global__ __launch_bounds__(256) void gemm0_kernel(
    const float* __restrict__ stat, const float* __restrict__ dyn0,
    const float* __restrict__ dyn1, const float4* __restrict__ w2g4,
    const float* __restrict__ asrc0, const float* __restrict__ atrg0,
    __half2* __restrict__ hp0h, float* __restrict__ s0, float* __restrict__ t0,
    int n_nodes)
{
    __shared__ __half2 w2_s[64 * 128];   // 32KB, layout [f2][c]
    int t = threadIdx.x;
    {
        float4* wdst = reinterpret_cast<float4*>(w2_s);
#pragma unroll
        for (int i = 0; i < 8; ++i) wdst[t + i * 256] = w2g4[t + i * 256];
    }
    __syncthreads();

    int cg = t & 31, ns = t >> 5;
    int c0 = cg * 4;
    int h = c0 >> 4, o0 = c0 & 15;
    float4 asv = *reinterpret_cast<const float4*>(&asrc0[h * 16 + o0]);
    float4 atv = *reinterpret_cast<const float4*>(&atrg0[h * 16 + o0]);

    int nb = blockIdx.x * (8 * NPT) + ns * NPT;
    int nn[NPT], nc[NPT];
#pragma unroll
    for (int i = 0; i < NPT; ++i) { nn[i] = nb + i; nc[i] = min(nn[i], n_nodes - 1); }

    float acc[NPT][4];
#pragma unroll
    for (int i = 0; i < NPT; ++i)
#pragma unroll
        for (int j = 0; j < 4; ++j) acc[i][j] = 0.f;

#define SEG(PTR, FDIM, FQN, F2BASE)                                              \
    _Pragma("unroll 2")                                                          \
    for (int fq = 0; fq < FQN; ++fq) {                                           \
        __half2 eh[NPT][2];                                                      \
        _Pragma("unroll")                                                        \
        for (int i = 0; i < NPT; ++i) {                                          \
            float4 v = *reinterpret_cast<const float4*>(&PTR[(size_t)nc[i] * FDIM + fq * 4]); \
            eh[i][0] = __floats2half2_rn(v.x, v.y);                              \
            eh[i][1] = __floats2half2_rn(v.z, v.w);                              \
        }                                                                        \
        _Pragma("unroll")                                                        \
        for (int p = 0; p < 2; ++p) {                                            \
            F4H wu;                                                              \
            wu.f = *reinterpret_cast<const float4*>(&w2_s[(F2BASE + fq * 2 + p) * 128 + c0]); \
            _Pragma("unroll")                                                    \
            for (int i = 0; i < NPT; ++i) {                                      \
                acc[i][0] = fdot2(eh[i][p], wu.h[0], acc[i][0]);                 \
                acc[i][1] = fdot2(eh[i][p], wu.h[1], acc[i][1]);                 \
                acc[i][2] = fdot2(eh[i][p], wu.h[2], acc[i][2]);                 \
                acc[i][3] = fdot2(eh[i][p], wu.h[3], acc[i][3]);                 \
            }                                                                    \
        }                                                                        \
    }

    SEG(dyn0, 32, 8, 0)
    SEG(dyn1, 32, 8, 16)
    SEG(stat, 64, 16, 32)
#undef SEG

#pragma unroll
    for (int i = 0; i < NPT; ++i) {
        bool valid = nn[i] < n_nodes;
        if (valid) {
            hp0h[(size_t)nn[i] * 64 + (c0 >> 1)]     = __floats2half2_rn(acc[i][0], acc[i][1]);
            hp0h[(size_t)nn[i] * 64 + (c0 >> 1) + 1] = __floats2half2_rn(acc[i][2], acc[i][3]);
        }
        float ps = acc[i][0] * asv.x + acc[i][1] * asv.y + acc[i][2] * asv.z + acc[i][3] * asv.w;
        float pt = acc[i][0] * atv.x + acc[i][1] * atv.y + acc[i][2] * atv.z + acc[i][3] * atv.w;
        ps += __shfl_xor(ps, 1); ps += __shfl_xor(ps, 2);
        pt += __shfl_xor(pt, 1); pt += __shfl_xor(pt, 2);
        if ((cg & 3) == 0 && valid) {
            s0[nn[i] * 8 + h] = ps;
            t0[nn[i] * 8 + h] = pt;
        }
    }
}

// ---------------- Layer-0 aggregate: one WAVE per target node ----------------
#define CH 64
__global__ __launch_bounds__(256) void node_accum0_kernel(
    const int* __restrict__ rowptr, const int* __restrict__ colsrc,
    const float* __restrict__ s0, const float* __restrict__ t0,
    const __half2* __restrict__ hp0h, const float* __restrict__ w1,
    const float* __restrict__ asrc1, const float* __restrict__ atrg1,
    float4* __restrict__ pk1, float* __restrict__ t1, int n_nodes)
{
    __shared__ int   se_s[4][CH];
    __shared__ float p_s[4][CH * 8];

    int w = threadIdx.x >> 6;
    int l = threadIdx.x & 63;
    int n = blockIdx.x * 4 + w;
    if (n >= n_nodes) return;

    int start = rowptr[n];
    int deg = rowptr[n + 1] - start;
    int hl = l & 7;          // head for p-compute
    int hc = l >> 3;         // head of my channels
    float tval = t0[n * 8 + hl];
    const float* pw = p_s[w];

    float acc0 = 0.f, acc1 = 0.f, dsum = 0.f;
    for (int chunk = 0; chunk < deg; chunk += CH) {
        int m = min(CH, deg - chunk);
        if (l < m) se_s[w][l] = colsrc[start + chunk + l];
        __builtin_amdgcn_wave_barrier();
        int iters = (m + 7) >> 3;
        for (int r = 0; r < iters; ++r) {
            int e = r * 8 + (l >> 3);
            float p = 0.f;
            if (e < m) {
                int se = se_s[w][e];
                float x = s0[se * 8 + hl] + tval;
                p = __expf(lrelu02(x) - ESHIFT);
            }
            p_s[w][r * 64 + l] = p;   // == p_s[e*8 + hl]
            dsum += p;
        }
        __builtin_amdgcn_wave_barrier();
        int e = 0;
        for (; e + 4 <= m; e += 4) {
            int sa = se_s[w][e + 0], sb = se_s[w][e + 1];
            int sc = se_s[w][e + 2], sd = se_s[w][e + 3];
            float2 fa = __half22float2(hp0h[(size_t)sa * 64 + l]);
            float2 fb = __half22float2(hp0h[(size_t)sb * 64 + l]);
            float2 fc = __half22float2(hp0h[(size_t)sc * 64 + l]);
            float2 fd = __half22float2(hp0h[(size_t)sd * 64 + l]);
            float pa = pw[(e + 0) * 8 + hc], pb = pw[(e + 1) * 8 + hc];
            float pc2 = pw[(e + 2) * 8 + hc], pd = pw[(e + 3) * 8 + hc];
            acc0 += fa.x * pa; acc1 += fa.y * pa;
            acc0 += fb.x * pb; acc1 += fb.y * pb;
            acc0 += fc.x * pc2; acc1 += fc.y * pc2;
            acc0 += fd.x * pd; acc1 += fd.y * pd;
        }
        for (; e < m; ++e) {
            int sa = se_s[w][e];
            float2 fa = __half22float2(hp0h[(size_t)sa * 64 + l]);
            float pa = pw[e * 8 + hc];
            acc0 += fa.x * pa; acc1 += fa.y * pa;
        }
        __builtin_amdgcn_wave_barrier();
    }

    dsum += __shfl_xor(dsum, 8);
    dsum += __shfl_xor(dsum, 16);
    dsum += __shfl_xor(dsum, 32);
    float denom = __shfl(dsum, hc);
    float inv = 1.f / (denom + 1e-16f);
    float v0 = acc0 * inv; v0 = v0 > 0.f ? v0 : expm1f(v0);
    float v1 = acc1 * inv; v1 = v1 > 0.f ? v1 : expm1f(v1);

    float4 wv = *reinterpret_cast<const float4*>(&w1[l * 4]);
    float r0 = v0 * wv.x + v1 * wv.z;
    float r1 = v0 * wv.y + v1 * wv.w;
#pragma unroll
    for (int off = 32; off > 0; off >>= 1) {
        r0 += __shfl_down(r0, off);
        r1 += __shfl_down(r1, off);
    }
    if (l == 0) {
        float s1v = r0 * asrc1[0] + r1 * asrc1[1];
        float t1v = r0 * atrg1[0] + r1 * atrg1[1];
        float4 pk; pk.x = r0; pk.y = r1; pk.z = s1v; pk.w = 0.f;
        pk1[n] = pk;
        t1[n] = t1v;
    }
}

// ---------------- Layer-1 aggregate + mean + log_softmax -> out ----------------
__global__ __launch_bounds__(256) void node_accum1_kernel(
    const int* __restrict__ rowptr, const int* __restrict__ colsrc,
    const float4* __restrict__ pk1, const float* __restrict__ t1,
    float* __restrict__ out, int n_nodes)
{
    int lane = threadIdx.x & 63;
    int n = blockIdx.x * 4 + (threadIdx.x >> 6);
    if (n >= n_nodes) return;
    int start = rowptr[n], deg = rowptr[n + 1] - start;
    float tn = t1[n];
    float d = 0.f, a0 = 0.f, a1 = 0.f;
    for (int i = lane; i < deg; i += 64) {
        int se = colsrc[start + i];
        float4 q = pk1[se];
        float p = __expf(lrelu02(q.z + tn) - ESHIFT);
        d += p;
        a0 += p * q.x;
        a1 += p * q.y;
    }
#pragma unroll
    for (int off = 32; off > 0; off >>= 1) {
        d  += __shfl_down(d, off);
        a0 += __shfl_down(a0, off);
        a1 += __shfl_down(a1, off);
    }
    if (lane == 0) {
        float inv = 1.f / (d + 1e-16f);
        float x0 = a0 * inv, x1 = a1 * inv;
        float m = fmaxf(x0, x1);
        float lse = m + logf(__expf(x0 - m) + __expf(x1 - m));
        out[n * 2 + 0] = x0 - lse;
        out[n * 2 + 1] = x1 - lse;
    }
}

extern "C" void kernel_launch(void* const* d_in, const int* in_sizes, int n_in,
                              void* d_out, int out_size, void* d_ws, size_t ws_size,
                              hipStream_t stream) {
    const float* stat  = (const float*)d_in[0];
    const float* dyn0  = (const float*)d_in[1];
    const float* dyn1  = (const float*)d_in[2];
    const int*   src   = (const int*)d_in[3];
    const int*   trg   = (const int*)d_in[4];
    const float* w0    = (const float*)d_in[5];
    const float* asrc0 = (const float*)d_in[6];
    const float* atrg0 = (const float*)d_in[7];
    const float* w1    = (const float*)d_in[8];
    const float* asrc1 = (const float*)d_in[9];
    const float* atrg1 = (const float*)d_in[10];
    float* out = (float*)d_out;

    const int N = in_sizes[0] / 64;   // 50000
    const int E = in_sizes[3];        // 800000
    const int NBK = (N + 255) >> 8;   // 196 buckets of 256 nodes
    const int CHUNK = (E + NCHUNK - 1) / NCHUNK;
    const int NPB = 8 * NPT;          // nodes per block (16)
    const int NTB = (N + NPB - 1) / NPB;  // 3125 blocks

    // ---- workspace layout ----
    float* ws = (float*)d_ws;
    size_t off = 0;
    // hp0h region (N*64 floats = 12.8MB); staging pairs (E int2 = 6.4MB) alias it
    __half2* hp0h = (__half2*)(ws + off);
    int2*    stage = (int2*)(ws + off);
    off += (size_t)N * 64;
    float* s0  = ws + off; off += (size_t)N * 8;
    float* t0  = ws + off; off += (size_t)N * 8;
    float4* pk1 = (float4*)(ws + off); off += (size_t)N * 4;
    float* t1  = ws + off; off += (size_t)N;
    __half2* w2g = (__half2*)(ws + off); off += 8192;   // 32KB packed W
    off = (off + 3) & ~(size_t)3;
    int* iws      = (int*)(ws + off);
    int* rowptr   = iws;                        // NBK*256 + 1
    int* colsrc   = rowptr + NBK * 256 + 1;     // E
    int* H        = colsrc + E;                 // NCHUNK*NBK
    int* basearr  = H + NCHUNK * NBK;           // NCHUNK*NBK
    int* bktstart = basearr + NCHUNK * NBK;     // NBK+1

    // ---- CSR build (tile counting sort, no global atomics) ----
    sort_hist_kernel<<<NCHUNK, 1024, 0, stream>>>(trg, H, E, NBK, CHUNK);
    sort_scan_kernel<<<1, 256, 0, stream>>>(H, basearr, bktstart, rowptr, NBK, E);
    sort_scatter_kernel<<<NCHUNK, 1024, 0, stream>>>(src, trg, basearr, stage, E, NBK, CHUNK);
    sort_finalize_kernel<<<NBK, 256, 0, stream>>>(stage, bktstart, rowptr, colsrc, NBK);

    // ---- W pre-pack, then LDS-W layer-0 projection + scores ----
    wconv_kernel<<<32, 256, 0, stream>>>(w0, w2g);
    gemm0_kernel<<<NTB, 256, 0, stream>>>(
        stat, dyn0, dyn1, (const float4*)w2g, asrc0, atrg0, hp0h, s0, t0, N);

    // ---- layer 0 aggregate + ELU + W1 + layer-1 scores (wave per node) ----
    node_accum0_kernel<<<(N + 3) / 4, 256, 0, stream>>>(
        rowptr, colsrc, s0, t0, hp0h, w1, asrc1, atrg1, pk1, t1, N);

    // ---- layer 1 aggregate + mean + log_softmax ----
    node_accum1_kernel<<<(N + 3) / 4, 256, 0, stream>>>(
        rowptr, colsrc, pk1, t1, out, N);
}